// Round 1
// baseline (8953.443 us; speedup 1.0000x reference)
//
#include <hip/hip_runtime.h>

#define T_ 64
#define B_ 64
#define S_ 128
#define E_ 512
#define H_ 1024

typedef __attribute__((ext_vector_type(8))) short short8;
typedef __attribute__((ext_vector_type(4))) short short4v;
typedef __attribute__((ext_vector_type(4))) float f32x4;

static __device__ __forceinline__ float bf2f(ushort u) {
  union { float f; unsigned u; } x; x.u = ((unsigned)u) << 16; return x.f;
}
static __device__ __forceinline__ ushort f2bf(float f) {
  union { float f; unsigned u; } x; x.f = f;
  unsigned r = 0x7FFFu + ((x.u >> 16) & 1u);
  return (ushort)((x.u + r) >> 16);
}
static __device__ __forceinline__ float sigm(float x) {
  return 1.f / (1.f + expf(-x));
}

// ---------------------------------------------------------------------------
__global__ __launch_bounds__(256) void k_cvt(const float* __restrict__ src,
                                             ushort* __restrict__ dst, int n4) {
  int i = blockIdx.x * 256 + threadIdx.x;
  if (i >= n4) return;
  f32x4 v = ((const f32x4*)src)[i];
  short4v o;
  o[0] = (short)f2bf(v[0]); o[1] = (short)f2bf(v[1]);
  o[2] = (short)f2bf(v[2]); o[3] = (short)f2bf(v[3]);
  ((short4v*)dst)[i] = o;
}

// ---------------------------------------------------------------------------
// f32 (H,H) [k][d]  ->  bf16 (H,H) [d][k]  (transpose + convert, LDS tiled)
__global__ __launch_bounds__(256) void k_cvtT(const float* __restrict__ src,
                                              ushort* __restrict__ dst) {
  __shared__ ushort tile[32][33];
  const int bx = blockIdx.x & 31;   // d-tile
  const int by = blockIdx.x >> 5;   // k-tile
  const int lx = threadIdx.x & 31, ly = threadIdx.x >> 5;  // 32 x 8
#pragma unroll
  for (int i = 0; i < 32; i += 8)
    tile[ly + i][lx] = f2bf(src[(size_t)(by * 32 + ly + i) * H_ + bx * 32 + lx]);
  __syncthreads();
#pragma unroll
  for (int i = 0; i < 32; i += 8)
    dst[(size_t)(bx * 32 + ly + i) * H_ + by * 32 + lx] = tile[lx][ly + i];
}

// ---------------------------------------------------------------------------
// ctxp[m, d] = sum_k ctx[m, k] * WaT[d, k],  m = s*B+b.  f32 output.
__global__ __launch_bounds__(256) void k_ctxp(const ushort* __restrict__ ctx,
                                              const ushort* __restrict__ WaT,
                                              float* __restrict__ ctxp) {
  const int tid = threadIdx.x;
  const int wave = tid >> 6, lane = tid & 63;
  const int quad = lane >> 4, l16 = lane & 15;
  const int m0 = blockIdx.x * 64 + wave * 16;
  const int n0 = blockIdx.y * 64;
  const ushort* ar = ctx + (size_t)(m0 + l16) * H_;
  const int koff = quad * 8;
  f32x4 acc[4] = {};
  for (int k0 = 0; k0 < H_; k0 += 32) {
    int kk = k0 + koff;
    short8 a = *(const short8*)(ar + kk);
#pragma unroll
    for (int nt = 0; nt < 4; ++nt) {
      short8 b = *(const short8*)(WaT + (size_t)(n0 + nt * 16 + l16) * H_ + kk);
      acc[nt] = __builtin_amdgcn_mfma_f32_16x16x32_bf16(a, b, acc[nt], 0, 0, 0);
    }
  }
#pragma unroll
  for (int nt = 0; nt < 4; ++nt)
#pragma unroll
    for (int r = 0; r < 4; ++r)
      ctxp[(size_t)(m0 + quad * 4 + r) * H_ + n0 + nt * 16 + l16] = acc[nt][r];
}

// ---------------------------------------------------------------------------
__global__ __launch_bounds__(256) void k_init(const float* __restrict__ h0in,
                                              ushort* __restrict__ h0bf,
                                              ushort* __restrict__ h1bf,
                                              ushort* __restrict__ feed,
                                              unsigned* __restrict__ flags) {
  int i = blockIdx.x * 256 + threadIdx.x;
  h0bf[i] = f2bf(h0in[i]);
  h1bf[i] = f2bf(h0in[B_ * H_ + i]);
  feed[i] = 0;
  if (blockIdx.x == 0) flags[threadIdx.x * 16] = 0;  // arrival flags + release word
}

// ---------------------------------------------------------------------------
// Grid barrier: per-block arrival flags (64B apart); block 0 collects and
// broadcasts via flags[0]. Relaxed polls + __threadfence acq/rel.
static __device__ __forceinline__ void grid_bar(unsigned* flags, unsigned gen) {
  __syncthreads();
  if (blockIdx.x == 0) {
    const int tid = threadIdx.x;
    if (tid > 0) {
      while (__hip_atomic_load(&flags[tid * 16], __ATOMIC_RELAXED,
                               __HIP_MEMORY_SCOPE_AGENT) < gen)
        __builtin_amdgcn_s_sleep(2);
    }
    __syncthreads();
    if (tid == 0) {
      __threadfence();
      __hip_atomic_store(&flags[0], gen, __ATOMIC_RELAXED,
                         __HIP_MEMORY_SCOPE_AGENT);
    }
    __syncthreads();
  } else {
    if (threadIdx.x == 0) {
      __threadfence();
      __hip_atomic_store(&flags[blockIdx.x * 16], gen, __ATOMIC_RELAXED,
                         __HIP_MEMORY_SCOPE_AGENT);
      while (__hip_atomic_load(&flags[0], __ATOMIC_RELAXED,
                               __HIP_MEMORY_SCOPE_AGENT) < gen)
        __builtin_amdgcn_s_sleep(2);
      __threadfence();
    }
    __syncthreads();
  }
}

// ---------------------------------------------------------------------------
struct FusedP {
  const ushort* inp;
  const ushort* Wih0; const ushort* Whh0;
  const ushort* Wih1; const ushort* Whh1;
  const ushort* Wout;
  const ushort* ctx;
  const float* ctxp;
  const float* bih0; const float* bhh0;
  const float* bih1; const float* bhh1;
  const float* c0in;
  ushort* h0A; ushort* h0B; ushort* h1A; ushort* h1B;
  ushort* feed; ushort* cvec;
  float* outs; float* hF; float* cF; float* attns;
  unsigned* flags;
};

// Persistent kernel: whole T-loop, 256 blocks x 256 threads, 4 barriers/step.
__global__ __launch_bounds__(256, 1) void k_fused(FusedP p) {
  __shared__ float st[4][16][17];
  __shared__ float al[S_];
  const int blk = blockIdx.x;
  const int tid = threadIdx.x;
  const int wave = tid >> 6, lane = tid & 63;
  const int quad = lane >> 4, l16 = lane & 15;

  // cell states in registers for all T steps (thread owns one (b,j) per layer)
  const int own_b = 16 * wave + (lane & 15);
  const int own_j = blk * 4 + (lane >> 4);
  const int own_idx = own_b * H_ + own_j;
  float c0reg = p.c0in[own_idx];
  float c1reg = p.c0in[B_ * H_ + own_idx];

  unsigned gen = 0;

  for (int t = 0; t < T_; ++t) {
    const int cur = t & 1;
    const ushort* h0prev = cur ? p.h0B : p.h0A;
    ushort* h0new = cur ? p.h0A : p.h0B;
    const ushort* h1prev = cur ? p.h1B : p.h1A;
    ushort* h1new = cur ? p.h1A : p.h1B;
    const int last = (t == T_ - 1);

    // ---- phase 1: LSTM layer 0 ----
    {
      const int j0 = blk * 4;
      const int arow = 16 * wave + l16;
      const ushort* er = p.inp + ((size_t)t * B_ + arow) * E_;
      const ushort* fr = p.feed + (size_t)arow * H_;
      const ushort* hr = h0prev + (size_t)arow * H_;
      const int n = (l16 >> 2) * H_ + j0 + (l16 & 3);
      const ushort* wihB = p.Wih0 + (size_t)n * (E_ + H_);
      const ushort* whhB = p.Whh0 + (size_t)n * H_;
      const int koff = quad * 8;
      f32x4 acc = {};
      for (int k0 = 0; k0 < E_ + 2 * H_; k0 += 32) {
        int kk = k0 + koff;
        short8 a;
        if (kk < E_)            a = *(const short8*)(er + kk);
        else if (kk < E_ + H_)  a = *(const short8*)(fr + (kk - E_));
        else                    a = *(const short8*)(hr + (kk - E_ - H_));
        short8 b = (kk < E_ + H_) ? *(const short8*)(wihB + kk)
                                  : *(const short8*)(whhB + (kk - E_ - H_));
        acc = __builtin_amdgcn_mfma_f32_16x16x32_bf16(a, b, acc, 0, 0, 0);
      }
#pragma unroll
      for (int r = 0; r < 4; ++r) st[wave][quad * 4 + r][l16] = acc[r];
      const int bl = lane & 15, jj = lane >> 4;
      const int b = 16 * wave + bl, j = j0 + jj;
      float gi = st[wave][bl][0 + jj]  + p.bih0[j]           + p.bhh0[j];
      float gf = st[wave][bl][4 + jj]  + p.bih0[H_ + j]      + p.bhh0[H_ + j];
      float gg = st[wave][bl][8 + jj]  + p.bih0[2 * H_ + j]  + p.bhh0[2 * H_ + j];
      float go = st[wave][bl][12 + jj] + p.bih0[3 * H_ + j]  + p.bhh0[3 * H_ + j];
      const int idx = b * H_ + j;
      float cn = sigm(gf) * c0reg + sigm(gi) * tanhf(gg);
      float hn = sigm(go) * tanhf(cn);
      c0reg = cn;
      h0new[idx] = f2bf(hn);
      if (last) { p.hF[idx] = hn; p.cF[idx] = cn; }
    }
    grid_bar(p.flags, ++gen);

    // ---- phase 2: LSTM layer 1 ----
    {
      const int j0 = blk * 4;
      const int arow = 16 * wave + l16;
      const ushort* xr = h0new + (size_t)arow * H_;
      const ushort* hr = h1prev + (size_t)arow * H_;
      const int n = (l16 >> 2) * H_ + j0 + (l16 & 3);
      const ushort* wihB = p.Wih1 + (size_t)n * H_;
      const ushort* whhB = p.Whh1 + (size_t)n * H_;
      const int koff = quad * 8;
      f32x4 acc = {};
      for (int k0 = 0; k0 < 2 * H_; k0 += 32) {
        int kk = k0 + koff;
        short8 a = (kk < H_) ? *(const short8*)(xr + kk)
                             : *(const short8*)(hr + (kk - H_));
        short8 b = (kk < H_) ? *(const short8*)(wihB + kk)
                             : *(const short8*)(whhB + (kk - H_));
        acc = __builtin_amdgcn_mfma_f32_16x16x32_bf16(a, b, acc, 0, 0, 0);
      }
#pragma unroll
      for (int r = 0; r < 4; ++r) st[wave][quad * 4 + r][l16] = acc[r];
      const int bl = lane & 15, jj = lane >> 4;
      const int b = 16 * wave + bl, j = j0 + jj;
      float gi = st[wave][bl][0 + jj]  + p.bih1[j]           + p.bhh1[j];
      float gf = st[wave][bl][4 + jj]  + p.bih1[H_ + j]      + p.bhh1[H_ + j];
      float gg = st[wave][bl][8 + jj]  + p.bih1[2 * H_ + j]  + p.bhh1[2 * H_ + j];
      float go = st[wave][bl][12 + jj] + p.bih1[3 * H_ + j]  + p.bhh1[3 * H_ + j];
      const int idx = b * H_ + j;
      float cn = sigm(gf) * c1reg + sigm(gi) * tanhf(gg);
      float hn = sigm(go) * tanhf(cn);
      c1reg = cn;
      h1new[idx] = f2bf(hn);
      if (last) { p.hF[B_ * H_ + idx] = hn; p.cF[B_ * H_ + idx] = cn; }
    }
    grid_bar(p.flags, ++gen);

    // ---- phase 3: attention (score + softmax + cvec), blocks 0..63 ----
    if (blk < B_) {
      const int b = blk;
      float qreg[16];
#pragma unroll
      for (int c = 0; c < 4; ++c) {
        short4v v = *(const short4v*)(h1new + (size_t)b * H_ + c * 256 + lane * 4);
#pragma unroll
        for (int j2 = 0; j2 < 4; ++j2) qreg[c * 4 + j2] = bf2f((ushort)v[j2]);
      }
#pragma unroll 4
      for (int i = 0; i < 32; ++i) {
        const int s = wave * 32 + i;
        const float* row = p.ctxp + ((size_t)s * B_ + b) * H_;
        float pr = 0.f;
#pragma unroll
        for (int c = 0; c < 4; ++c) {
          f32x4 v = *(const f32x4*)(row + c * 256 + lane * 4);
          pr += v[0] * qreg[c * 4 + 0] + v[1] * qreg[c * 4 + 1] +
                v[2] * qreg[c * 4 + 2] + v[3] * qreg[c * 4 + 3];
        }
#pragma unroll
        for (int off = 32; off; off >>= 1) pr += __shfl_down(pr, off);
        if (lane == 0) al[s] = pr;
      }
      __syncthreads();
      if (wave == 0) {
        float m = fmaxf(al[lane], al[lane + 64]);
#pragma unroll
        for (int off = 32; off; off >>= 1) m = fmaxf(m, __shfl_down(m, off));
        m = __shfl(m, 0);
        float e0 = expf(al[lane] - m), e1 = expf(al[lane + 64] - m);
        float s2 = e0 + e1;
#pragma unroll
        for (int off = 32; off; off >>= 1) s2 += __shfl_down(s2, off);
        s2 = __shfl(s2, 0);
        float inv = 1.f / s2;
        al[lane] = e0 * inv;
        al[lane + 64] = e1 * inv;
      }
      __syncthreads();
      if (tid < S_) p.attns[((size_t)t * B_ + b) * S_ + tid] = al[tid];
      {
        const int d0 = tid * 4;
        const ushort* cb = p.ctx + (size_t)b * H_ + d0;
        float a0 = 0.f, a1 = 0.f, a2 = 0.f, a3 = 0.f;
#pragma unroll 4
        for (int s = 0; s < S_; ++s) {
          short4v v = *(const short4v*)(cb + (size_t)s * B_ * H_);
          float w = al[s];
          a0 += w * bf2f((ushort)v[0]);
          a1 += w * bf2f((ushort)v[1]);
          a2 += w * bf2f((ushort)v[2]);
          a3 += w * bf2f((ushort)v[3]);
        }
        short4v o;
        o[0] = (short)f2bf(a0); o[1] = (short)f2bf(a1);
        o[2] = (short)f2bf(a2); o[3] = (short)f2bf(a3);
        *(short4v*)(p.cvec + (size_t)b * H_ + d0) = o;
      }
    }
    grid_bar(p.flags, ++gen);

    // ---- phase 4: output projection, blocks 0..63 ----
    if (blk < 64) {
      const int j0 = blk * 16;
      const int arow = 16 * wave + l16;
      const ushort* cr = p.cvec + (size_t)arow * H_;
      const ushort* hr2 = h1new + (size_t)arow * H_;
      const ushort* wr = p.Wout + (size_t)(j0 + l16) * (2 * H_);
      const int koff = quad * 8;
      f32x4 acc = {};
      for (int k0 = 0; k0 < 2 * H_; k0 += 32) {
        int kk = k0 + koff;
        short8 a = (kk < H_) ? *(const short8*)(cr + kk)
                             : *(const short8*)(hr2 + (kk - H_));
        short8 b = *(const short8*)(wr + kk);
        acc = __builtin_amdgcn_mfma_f32_16x16x32_bf16(a, b, acc, 0, 0, 0);
      }
      const int j = j0 + l16;
#pragma unroll
      for (int r = 0; r < 4; ++r) {
        int b = 16 * wave + quad * 4 + r;
        float v = tanhf(acc[r]);
        p.outs[(size_t)t * B_ * H_ + b * H_ + j] = v;
        p.feed[b * H_ + j] = f2bf(v);
      }
    }
    grid_bar(p.flags, ++gen);
  }
}

// ---------------------------------------------------------------------------
extern "C" void kernel_launch(void* const* d_in, const int* in_sizes, int n_in,
                              void* d_out, int out_size, void* d_ws, size_t ws_size,
                              hipStream_t stream) {
  const float* inpf  = (const float*)d_in[0];
  const float* ctxf  = (const float*)d_in[1];
  const float* h0in  = (const float*)d_in[2];
  const float* c0in  = (const float*)d_in[3];
  const float* Wih0f = (const float*)d_in[4];
  const float* bih0  = (const float*)d_in[5];
  const float* Whh0f = (const float*)d_in[6];
  const float* bhh0  = (const float*)d_in[7];
  const float* Wih1f = (const float*)d_in[8];
  const float* bih1  = (const float*)d_in[9];
  const float* Whh1f = (const float*)d_in[10];
  const float* bhh1  = (const float*)d_in[11];
  const float* Waf   = (const float*)d_in[12];
  const float* Woutf = (const float*)d_in[13];

  float* out = (float*)d_out;
  float* outs  = out;                              // (T,B,H)
  float* hF    = out + (size_t)T_ * B_ * H_;       // (2,B,H)
  float* cF    = hF + 2 * B_ * H_;                 // (2,B,H)
  float* attns = cF + 2 * B_ * H_;                 // (T,B,S)

  char* p = (char*)d_ws;
  auto take = [&](size_t bytes) -> char* {
    char* q = p;
    p += (bytes + 255) & ~(size_t)255;
    return q;
  };
  ushort* h0A  = (ushort*)take((size_t)B_ * H_ * 2);
  ushort* h0B  = (ushort*)take((size_t)B_ * H_ * 2);
  ushort* h1A  = (ushort*)take((size_t)B_ * H_ * 2);
  ushort* h1B  = (ushort*)take((size_t)B_ * H_ * 2);
  ushort* feed = (ushort*)take((size_t)B_ * H_ * 2);
  ushort* cvec = (ushort*)take((size_t)B_ * H_ * 2);
  unsigned* flags = (unsigned*)take(256 * 16 * sizeof(unsigned));
  ushort* WaT  = (ushort*)take((size_t)H_ * H_ * 2);
  float* ctxp  = (float*)take((size_t)S_ * B_ * H_ * 4);

  struct { const float* src; int n; } cv[7] = {
    {Wih0f, 4 * H_ * (E_ + H_)}, {Whh0f, 4 * H_ * H_},
    {Wih1f, 4 * H_ * H_},        {Whh1f, 4 * H_ * H_},
    {Woutf, 2 * H_ * H_},
    {inpf,  T_ * B_ * E_},       {ctxf,  S_ * B_ * H_},
  };
  ushort* cb[7];
  for (int i = 0; i < 7; ++i) {
    cb[i] = (ushort*)take((size_t)cv[i].n * 2);
    int n4 = cv[i].n / 4;
    k_cvt<<<(n4 + 255) / 256, 256, 0, stream>>>(cv[i].src, cb[i], n4);
  }
  const ushort *Wih0 = cb[0], *Whh0 = cb[1], *Wih1 = cb[2], *Whh1 = cb[3],
               *Wout = cb[4], *inp = cb[5], *ctx = cb[6];

  k_cvtT<<<(H_ / 32) * (H_ / 32), 256, 0, stream>>>(Waf, WaT);
  k_ctxp<<<dim3((S_ * B_) / 64, H_ / 64), 256, 0, stream>>>(ctx, WaT, ctxp);
  k_init<<<(B_ * H_) / 256, 256, 0, stream>>>(h0in, h0A, h1A, feed, flags);

  FusedP fp;
  fp.inp = inp; fp.Wih0 = Wih0; fp.Whh0 = Whh0; fp.Wih1 = Wih1; fp.Whh1 = Whh1;
  fp.Wout = Wout; fp.ctx = ctx; fp.ctxp = ctxp;
  fp.bih0 = bih0; fp.bhh0 = bhh0; fp.bih1 = bih1; fp.bhh1 = bhh1;
  fp.c0in = c0in;
  fp.h0A = h0A; fp.h0B = h0B; fp.h1A = h1A; fp.h1B = h1B;
  fp.feed = feed; fp.cvec = cvec;
  fp.outs = outs; fp.hF = hF; fp.cF = cF; fp.attns = attns;
  fp.flags = flags;
  void* kargs[] = {(void*)&fp};
  hipLaunchCooperativeKernel(k_fused, dim3(256), dim3(256), kargs, 0, stream);
}

// Round 2
// 6492.738 us; speedup vs baseline: 1.3790x; 1.3790x over previous
//
#include <hip/hip_runtime.h>

#define T_ 64
#define B_ 64
#define S_ 128
#define E_ 512
#define H_ 1024
#define BH (B_ * H_)

typedef __attribute__((ext_vector_type(8))) short short8;
typedef __attribute__((ext_vector_type(4))) short short4v;
typedef __attribute__((ext_vector_type(4))) float f32x4;

static __device__ __forceinline__ float bf2f(ushort u) {
  union { float f; unsigned u; } x; x.u = ((unsigned)u) << 16; return x.f;
}
static __device__ __forceinline__ ushort f2bf(float f) {
  union { float f; unsigned u; } x; x.f = f;
  unsigned r = 0x7FFFu + ((x.u >> 16) & 1u);
  return (ushort)((x.u + r) >> 16);
}
static __device__ __forceinline__ float sigm(float x) {
  return 1.f / (1.f + expf(-x));
}

// device-scope (sc1) relaxed atomics: write-through to the coherence point
// (Infinity Cache) WITHOUT any L2 writeback/invalidate.
static __device__ __forceinline__ void st32_dev(unsigned* p, unsigned v) {
  __hip_atomic_store(p, v, __ATOMIC_RELAXED, __HIP_MEMORY_SCOPE_AGENT);
}
static __device__ __forceinline__ unsigned ld32_dev(const unsigned* p) {
  return __hip_atomic_load(p, __ATOMIC_RELAXED, __HIP_MEMORY_SCOPE_AGENT);
}
static __device__ __forceinline__ void st64_dev(unsigned long long* p,
                                                unsigned long long v) {
  __hip_atomic_store(p, v, __ATOMIC_RELAXED, __HIP_MEMORY_SCOPE_AGENT);
}

// ---------------------------------------------------------------------------
__global__ __launch_bounds__(256) void k_cvt(const float* __restrict__ src,
                                             ushort* __restrict__ dst, int n4) {
  int i = blockIdx.x * 256 + threadIdx.x;
  if (i >= n4) return;
  f32x4 v = ((const f32x4*)src)[i];
  short4v o;
  o[0] = (short)f2bf(v[0]); o[1] = (short)f2bf(v[1]);
  o[2] = (short)f2bf(v[2]); o[3] = (short)f2bf(v[3]);
  ((short4v*)dst)[i] = o;
}

// ---------------------------------------------------------------------------
// f32 (H,H) [k][d]  ->  bf16 (H,H) [d][k]  (transpose + convert, LDS tiled)
__global__ __launch_bounds__(256) void k_cvtT(const float* __restrict__ src,
                                              ushort* __restrict__ dst) {
  __shared__ ushort tile[32][33];
  const int bx = blockIdx.x & 31;   // d-tile
  const int by = blockIdx.x >> 5;   // k-tile
  const int lx = threadIdx.x & 31, ly = threadIdx.x >> 5;  // 32 x 8
#pragma unroll
  for (int i = 0; i < 32; i += 8)
    tile[ly + i][lx] = f2bf(src[(size_t)(by * 32 + ly + i) * H_ + bx * 32 + lx]);
  __syncthreads();
#pragma unroll
  for (int i = 0; i < 32; i += 8)
    dst[(size_t)(bx * 32 + ly + i) * H_ + by * 32 + lx] = tile[lx][ly + i];
}

// ---------------------------------------------------------------------------
// ctxp[m, d] = sum_k ctx[m, k] * WaT[d, k],  m = s*B+b.  f32 output.
__global__ __launch_bounds__(256) void k_ctxp(const ushort* __restrict__ ctx,
                                              const ushort* __restrict__ WaT,
                                              float* __restrict__ ctxp) {
  const int tid = threadIdx.x;
  const int wave = tid >> 6, lane = tid & 63;
  const int quad = lane >> 4, l16 = lane & 15;
  const int m0 = blockIdx.x * 64 + wave * 16;
  const int n0 = blockIdx.y * 64;
  const ushort* ar = ctx + (size_t)(m0 + l16) * H_;
  const int koff = quad * 8;
  f32x4 acc[4] = {};
  for (int k0 = 0; k0 < H_; k0 += 32) {
    int kk = k0 + koff;
    short8 a = *(const short8*)(ar + kk);
#pragma unroll
    for (int nt = 0; nt < 4; ++nt) {
      short8 b = *(const short8*)(WaT + (size_t)(n0 + nt * 16 + l16) * H_ + kk);
      acc[nt] = __builtin_amdgcn_mfma_f32_16x16x32_bf16(a, b, acc[nt], 0, 0, 0);
    }
  }
#pragma unroll
  for (int nt = 0; nt < 4; ++nt)
#pragma unroll
    for (int r = 0; r < 4; ++r)
      ctxp[(size_t)(m0 + quad * 4 + r) * H_ + n0 + nt * 16 + l16] = acc[nt][r];
}

// ---------------------------------------------------------------------------
__global__ __launch_bounds__(256) void k_init(const float* __restrict__ h0in,
                                              ushort* __restrict__ h0b,
                                              ushort* __restrict__ h1b,
                                              ushort* __restrict__ fdb,
                                              unsigned* __restrict__ flags) {
  int i = blockIdx.x * 256 + threadIdx.x;
  h0b[i] = f2bf(h0in[i]);
  h1b[i] = f2bf(h0in[BH + i]);
  fdb[i] = 0;
  if (blockIdx.x == 0) flags[threadIdx.x * 16] = 0;
}

// ---------------------------------------------------------------------------
// Grid barrier WITHOUT cache-invalidating fences. __syncthreads drains each
// thread's vmcnt (so prior sc1 stores are at the coherence point); flags are
// device-scope relaxed atomics (sc1). No buffer_inv / buffer_wbl2 -> L2 stays
// hot (weights) across all barriers.
static __device__ __forceinline__ void grid_bar(unsigned* flags, unsigned gen) {
  __syncthreads();
  if (blockIdx.x == 0) {
    const int tid = threadIdx.x;
    if (tid > 0) {
      while (ld32_dev(&flags[tid * 16]) < gen) __builtin_amdgcn_s_sleep(4);
    }
    __syncthreads();
    if (tid == 0) st32_dev(&flags[0], gen);
    __syncthreads();
  } else {
    if (threadIdx.x == 0) {
      st32_dev(&flags[blockIdx.x * 16], gen);
      while (ld32_dev(&flags[0]) < gen) __builtin_amdgcn_s_sleep(4);
    }
    __syncthreads();
  }
  asm volatile("" ::: "memory");
}

// ---------------------------------------------------------------------------
struct FusedP {
  const ushort* inp;
  const ushort* Wih0; const ushort* Whh0;
  const ushort* Wih1; const ushort* Whh1;
  const ushort* Wout;
  const ushort* ctx;
  const float* ctxp;
  const float* bih0; const float* bhh0;
  const float* bih1; const float* bhh1;
  const float* c0in;
  ushort* h0b;   // (T_+1) rotated buffers of (B,H) bf16 -- write-once
  ushort* h1b;   // (T_+1)
  ushort* fdb;   // (T_+1)
  ushort* cvb;   // (T_)
  float* outs; float* hF; float* cF; float* attns;
  unsigned* flags;
};

// Persistent kernel: whole T-loop, 256 blocks x 256 threads, 4 barriers/step.
// All inter-phase reads are PLAIN vectorized loads (legal: every inter-phase
// address is written exactly once per dispatch -> no stale L2 line possible).
// All inter-phase writes are packed device-scope (sc1) atomic stores.
__global__ __launch_bounds__(256, 1) void k_fused(FusedP p) {
  __shared__ float st[4][16][17];
  __shared__ float al[S_];
  const int blk = blockIdx.x;
  const int tid = threadIdx.x;
  const int wave = tid >> 6, lane = tid & 63;
  const int quad = lane >> 4, l16 = lane & 15;

  // cell states in registers for all T steps (thread owns one (b,j) per layer)
  const int own_b = 16 * wave + (lane & 15);
  const int own_j = blk * 4 + (lane >> 4);
  const int own_idx = own_b * H_ + own_j;
  float c0reg = p.c0in[own_idx];
  float c1reg = p.c0in[BH + own_idx];

  unsigned gen = 0;

  for (int t = 0; t < T_; ++t) {
    const ushort* h0prev = p.h0b + (size_t)t * BH;
    ushort* h0new       = p.h0b + (size_t)(t + 1) * BH;
    const ushort* h1prev = p.h1b + (size_t)t * BH;
    ushort* h1new       = p.h1b + (size_t)(t + 1) * BH;
    const ushort* feedr  = p.fdb + (size_t)t * BH;
    ushort* feedw       = p.fdb + (size_t)(t + 1) * BH;
    ushort* cv          = p.cvb + (size_t)t * BH;
    const int last = (t == T_ - 1);

    // ---- phase 1: LSTM layer 0 (gate-packed MFMA, 4 j-cols per block) ----
    {
      const int j0 = blk * 4;
      const int arow = 16 * wave + l16;
      const ushort* er = p.inp + ((size_t)t * B_ + arow) * E_;
      const ushort* fr = feedr + (size_t)arow * H_;
      const ushort* hr = h0prev + (size_t)arow * H_;
      const int n = (l16 >> 2) * H_ + j0 + (l16 & 3);
      const ushort* wihB = p.Wih0 + (size_t)n * (E_ + H_);
      const ushort* whhB = p.Whh0 + (size_t)n * H_;
      const int koff = quad * 8;
      f32x4 acc = {};
      for (int k0 = 0; k0 < E_ + 2 * H_; k0 += 32) {
        int kk = k0 + koff;
        short8 a;
        if (kk < E_)            a = *(const short8*)(er + kk);
        else if (kk < E_ + H_)  a = *(const short8*)(fr + (kk - E_));
        else                    a = *(const short8*)(hr + (kk - E_ - H_));
        short8 b = (kk < E_ + H_) ? *(const short8*)(wihB + kk)
                                  : *(const short8*)(whhB + (kk - E_ - H_));
        acc = __builtin_amdgcn_mfma_f32_16x16x32_bf16(a, b, acc, 0, 0, 0);
      }
#pragma unroll
      for (int r = 0; r < 4; ++r) st[wave][quad * 4 + r][l16] = acc[r];
      const int bl = lane & 15, jj = lane >> 4;
      const int b = 16 * wave + bl, j = j0 + jj;
      float gi = st[wave][bl][0 + jj]  + p.bih0[j]           + p.bhh0[j];
      float gf = st[wave][bl][4 + jj]  + p.bih0[H_ + j]      + p.bhh0[H_ + j];
      float gg = st[wave][bl][8 + jj]  + p.bih0[2 * H_ + j]  + p.bhh0[2 * H_ + j];
      float go = st[wave][bl][12 + jj] + p.bih0[3 * H_ + j]  + p.bhh0[3 * H_ + j];
      float cn = sigm(gf) * c0reg + sigm(gi) * tanhf(gg);
      float hn = sigm(go) * tanhf(cn);
      c0reg = cn;
      if (last) { p.hF[b * H_ + j] = hn; p.cF[b * H_ + j] = cn; }
      // pack 2 adjacent j (lanes l, l+16 share b) -> one 32-bit sc1 store
      unsigned u = f2bf(hn);
      unsigned up = __shfl_down(u, 16);
      if (!(jj & 1))
        st32_dev((unsigned*)h0new + b * (H_ / 2) + blk * 2 + (jj >> 1),
                 u | (up << 16));
    }
    grid_bar(p.flags, ++gen);

    // ---- phase 2: LSTM layer 1 ----
    {
      const int j0 = blk * 4;
      const int arow = 16 * wave + l16;
      const ushort* xr = h0new + (size_t)arow * H_;
      const ushort* hr = h1prev + (size_t)arow * H_;
      const int n = (l16 >> 2) * H_ + j0 + (l16 & 3);
      const ushort* wihB = p.Wih1 + (size_t)n * H_;
      const ushort* whhB = p.Whh1 + (size_t)n * H_;
      const int koff = quad * 8;
      f32x4 acc = {};
      for (int k0 = 0; k0 < 2 * H_; k0 += 32) {
        int kk = k0 + koff;
        short8 a = (kk < H_) ? *(const short8*)(xr + kk)
                             : *(const short8*)(hr + (kk - H_));
        short8 b = (kk < H_) ? *(const short8*)(wihB + kk)
                             : *(const short8*)(whhB + (kk - H_));
        acc = __builtin_amdgcn_mfma_f32_16x16x32_bf16(a, b, acc, 0, 0, 0);
      }
#pragma unroll
      for (int r = 0; r < 4; ++r) st[wave][quad * 4 + r][l16] = acc[r];
      const int bl = lane & 15, jj = lane >> 4;
      const int b = 16 * wave + bl, j = j0 + jj;
      float gi = st[wave][bl][0 + jj]  + p.bih1[j]           + p.bhh1[j];
      float gf = st[wave][bl][4 + jj]  + p.bih1[H_ + j]      + p.bhh1[H_ + j];
      float gg = st[wave][bl][8 + jj]  + p.bih1[2 * H_ + j]  + p.bhh1[2 * H_ + j];
      float go = st[wave][bl][12 + jj] + p.bih1[3 * H_ + j]  + p.bhh1[3 * H_ + j];
      float cn = sigm(gf) * c1reg + sigm(gi) * tanhf(gg);
      float hn = sigm(go) * tanhf(cn);
      c1reg = cn;
      if (last) { p.hF[BH + b * H_ + j] = hn; p.cF[BH + b * H_ + j] = cn; }
      unsigned u = f2bf(hn);
      unsigned up = __shfl_down(u, 16);
      if (!(jj & 1))
        st32_dev((unsigned*)h1new + b * (H_ / 2) + blk * 2 + (jj >> 1),
                 u | (up << 16));
    }
    grid_bar(p.flags, ++gen);

    // ---- phase 3: attention (score + softmax + cvec), blocks 0..63 ----
    if (blk < B_) {
      const int b = blk;
      float qreg[16];
#pragma unroll
      for (int c = 0; c < 4; ++c) {
        short4v v = *(const short4v*)(h1new + (size_t)b * H_ + c * 256 + lane * 4);
#pragma unroll
        for (int j2 = 0; j2 < 4; ++j2) qreg[c * 4 + j2] = bf2f((ushort)v[j2]);
      }
#pragma unroll 4
      for (int i = 0; i < 32; ++i) {
        const int s = wave * 32 + i;
        const float* row = p.ctxp + ((size_t)s * B_ + b) * H_;
        float pr = 0.f;
#pragma unroll
        for (int c = 0; c < 4; ++c) {
          f32x4 v = *(const f32x4*)(row + c * 256 + lane * 4);
          pr += v[0] * qreg[c * 4 + 0] + v[1] * qreg[c * 4 + 1] +
                v[2] * qreg[c * 4 + 2] + v[3] * qreg[c * 4 + 3];
        }
#pragma unroll
        for (int off = 32; off; off >>= 1) pr += __shfl_down(pr, off);
        if (lane == 0) al[s] = pr;
      }
      __syncthreads();
      if (wave == 0) {
        float m = fmaxf(al[lane], al[lane + 64]);
#pragma unroll
        for (int off = 32; off; off >>= 1) m = fmaxf(m, __shfl_down(m, off));
        m = __shfl(m, 0);
        float e0 = expf(al[lane] - m), e1 = expf(al[lane + 64] - m);
        float s2 = e0 + e1;
#pragma unroll
        for (int off = 32; off; off >>= 1) s2 += __shfl_down(s2, off);
        s2 = __shfl(s2, 0);
        float inv = 1.f / s2;
        al[lane] = e0 * inv;
        al[lane + 64] = e1 * inv;
      }
      __syncthreads();
      if (tid < S_) p.attns[((size_t)t * B_ + b) * S_ + tid] = al[tid];
      {
        const int d0 = tid * 4;
        const ushort* cb = p.ctx + (size_t)b * H_ + d0;
        float a0 = 0.f, a1 = 0.f, a2 = 0.f, a3 = 0.f;
#pragma unroll 4
        for (int s = 0; s < S_; ++s) {
          short4v v = *(const short4v*)(cb + (size_t)s * B_ * H_);
          float w = al[s];
          a0 += w * bf2f((ushort)v[0]);
          a1 += w * bf2f((ushort)v[1]);
          a2 += w * bf2f((ushort)v[2]);
          a3 += w * bf2f((ushort)v[3]);
        }
        unsigned lo = (unsigned)f2bf(a0) | ((unsigned)f2bf(a1) << 16);
        unsigned hi = (unsigned)f2bf(a2) | ((unsigned)f2bf(a3) << 16);
        st64_dev((unsigned long long*)cv + b * (H_ / 4) + tid,
                 (unsigned long long)lo | ((unsigned long long)hi << 32));
      }
    }
    grid_bar(p.flags, ++gen);

    // ---- phase 4: output projection, blocks 0..63 (16 j-cols each) ----
    if (blk < 64) {
      const int j0 = blk * 16;
      const int arow = 16 * wave + l16;
      const ushort* cr = cv + (size_t)arow * H_;
      const ushort* hr2 = h1new + (size_t)arow * H_;
      const ushort* wr = p.Wout + (size_t)(j0 + l16) * (2 * H_);
      const int koff = quad * 8;
      f32x4 acc = {};
      for (int k0 = 0; k0 < 2 * H_; k0 += 32) {
        int kk = k0 + koff;
        short8 a = (kk < H_) ? *(const short8*)(cr + kk)
                             : *(const short8*)(hr2 + (kk - H_));
        short8 b = *(const short8*)(wr + kk);
        acc = __builtin_amdgcn_mfma_f32_16x16x32_bf16(a, b, acc, 0, 0, 0);
      }
      const int j = j0 + l16;
#pragma unroll
      for (int r = 0; r < 4; ++r) {
        int b = 16 * wave + quad * 4 + r;
        float v = tanhf(acc[r]);
        p.outs[(size_t)t * B_ * H_ + b * H_ + j] = v;
        // pack 2 adjacent j (lanes l16, l16+1) -> one 32-bit sc1 store
        unsigned u = f2bf(v);
        unsigned up = __shfl_down(u, 1);
        if (!(l16 & 1))
          st32_dev((unsigned*)feedw + b * (H_ / 2) + blk * 8 + (l16 >> 1),
                   u | (up << 16));
      }
    }
    grid_bar(p.flags, ++gen);
  }
}

// ---------------------------------------------------------------------------
extern "C" void kernel_launch(void* const* d_in, const int* in_sizes, int n_in,
                              void* d_out, int out_size, void* d_ws, size_t ws_size,
                              hipStream_t stream) {
  const float* inpf  = (const float*)d_in[0];
  const float* ctxf  = (const float*)d_in[1];
  const float* h0in  = (const float*)d_in[2];
  const float* c0in  = (const float*)d_in[3];
  const float* Wih0f = (const float*)d_in[4];
  const float* bih0  = (const float*)d_in[5];
  const float* Whh0f = (const float*)d_in[6];
  const float* bhh0  = (const float*)d_in[7];
  const float* Wih1f = (const float*)d_in[8];
  const float* bih1  = (const float*)d_in[9];
  const float* Whh1f = (const float*)d_in[10];
  const float* bhh1  = (const float*)d_in[11];
  const float* Waf   = (const float*)d_in[12];
  const float* Woutf = (const float*)d_in[13];

  float* out = (float*)d_out;
  float* outs  = out;                              // (T,B,H)
  float* hF    = out + (size_t)T_ * B_ * H_;       // (2,B,H)
  float* cF    = hF + 2 * BH;                      // (2,B,H)
  float* attns = cF + 2 * BH;                      // (T,B,S)

  char* p = (char*)d_ws;
  auto take = [&](size_t bytes) -> char* {
    char* q = p;
    p += (bytes + 255) & ~(size_t)255;
    return q;
  };
  ushort* h0b  = (ushort*)take((size_t)(T_ + 1) * BH * 2);
  ushort* h1b  = (ushort*)take((size_t)(T_ + 1) * BH * 2);
  ushort* fdb  = (ushort*)take((size_t)(T_ + 1) * BH * 2);
  ushort* cvb  = (ushort*)take((size_t)T_ * BH * 2);
  unsigned* flags = (unsigned*)take(256 * 16 * sizeof(unsigned));
  ushort* WaT  = (ushort*)take((size_t)H_ * H_ * 2);
  float* ctxp  = (float*)take((size_t)S_ * B_ * H_ * 4);

  struct { const float* src; int n; } cv[7] = {
    {Wih0f, 4 * H_ * (E_ + H_)}, {Whh0f, 4 * H_ * H_},
    {Wih1f, 4 * H_ * H_},        {Whh1f, 4 * H_ * H_},
    {Woutf, 2 * H_ * H_},
    {inpf,  T_ * B_ * E_},       {ctxf,  S_ * B_ * H_},
  };
  ushort* cb[7];
  for (int i = 0; i < 7; ++i) {
    cb[i] = (ushort*)take((size_t)cv[i].n * 2);
    int n4 = cv[i].n / 4;
    k_cvt<<<(n4 + 255) / 256, 256, 0, stream>>>(cv[i].src, cb[i], n4);
  }
  const ushort *Wih0 = cb[0], *Whh0 = cb[1], *Wih1 = cb[2], *Whh1 = cb[3],
               *Wout = cb[4], *inp = cb[5], *ctx = cb[6];

  k_cvtT<<<(H_ / 32) * (H_ / 32), 256, 0, stream>>>(Waf, WaT);
  k_ctxp<<<dim3((S_ * B_) / 64, H_ / 64), 256, 0, stream>>>(ctx, WaT, ctxp);
  k_init<<<BH / 256, 256, 0, stream>>>(h0in, h0b, h1b, fdb, flags);

  FusedP fp;
  fp.inp = inp; fp.Wih0 = Wih0; fp.Whh0 = Whh0; fp.Wih1 = Wih1; fp.Whh1 = Whh1;
  fp.Wout = Wout; fp.ctx = ctx; fp.ctxp = ctxp;
  fp.bih0 = bih0; fp.bhh0 = bhh0; fp.bih1 = bih1; fp.bhh1 = bhh1;
  fp.c0in = c0in;
  fp.h0b = h0b; fp.h1b = h1b; fp.fdb = fdb; fp.cvb = cvb;
  fp.outs = outs; fp.hF = hF; fp.cF = cF; fp.attns = attns;
  fp.flags = flags;
  void* kargs[] = {(void*)&fp};
  hipLaunchCooperativeKernel(k_fused, dim3(256), dim3(256), kargs, 0, stream);
}

// Round 3
// 5403.439 us; speedup vs baseline: 1.6570x; 1.2016x over previous
//
#include <hip/hip_runtime.h>

#define T_ 64
#define B_ 64
#define S_ 128
#define E_ 512
#define H_ 1024
#define BH (B_ * H_)

// LDS weight slice geometry (bf16 elements), +8 pad => row stride = 4 banks
#define W0ROW (E_ + 2 * H_ + 8)   // 2568
#define W1ROW (2 * H_ + 8)        // 2056
#define SMEM_BYTES ((16 * W0ROW + 16 * W1ROW) * 2)  // 147968 B

typedef __attribute__((ext_vector_type(8))) short short8;
typedef __attribute__((ext_vector_type(4))) short short4v;
typedef __attribute__((ext_vector_type(4))) float f32x4;

static __device__ __forceinline__ float bf2f(ushort u) {
  union { float f; unsigned u; } x; x.u = ((unsigned)u) << 16; return x.f;
}
static __device__ __forceinline__ ushort f2bf(float f) {
  union { float f; unsigned u; } x; x.f = f;
  unsigned r = 0x7FFFu + ((x.u >> 16) & 1u);
  return (ushort)((x.u + r) >> 16);
}
static __device__ __forceinline__ float sigm(float x) {
  return 1.f / (1.f + expf(-x));
}

// device-scope (sc1) relaxed atomics: write-through to the coherence point.
static __device__ __forceinline__ void st32_dev(unsigned* p, unsigned v) {
  __hip_atomic_store(p, v, __ATOMIC_RELAXED, __HIP_MEMORY_SCOPE_AGENT);
}
static __device__ __forceinline__ unsigned ld32_dev(const unsigned* p) {
  return __hip_atomic_load(p, __ATOMIC_RELAXED, __HIP_MEMORY_SCOPE_AGENT);
}
static __device__ __forceinline__ void st64_dev(unsigned long long* p,
                                                unsigned long long v) {
  __hip_atomic_store(p, v, __ATOMIC_RELAXED, __HIP_MEMORY_SCOPE_AGENT);
}

// ---------------------------------------------------------------------------
__global__ __launch_bounds__(256) void k_cvt(const float* __restrict__ src,
                                             ushort* __restrict__ dst, int n4) {
  int i = blockIdx.x * 256 + threadIdx.x;
  if (i >= n4) return;
  f32x4 v = ((const f32x4*)src)[i];
  short4v o;
  o[0] = (short)f2bf(v[0]); o[1] = (short)f2bf(v[1]);
  o[2] = (short)f2bf(v[2]); o[3] = (short)f2bf(v[3]);
  ((short4v*)dst)[i] = o;
}

// ---------------------------------------------------------------------------
// f32 (H,H) [k][d]  ->  bf16 (H,H) [d][k]  (transpose + convert, LDS tiled)
__global__ __launch_bounds__(256) void k_cvtT(const float* __restrict__ src,
                                              ushort* __restrict__ dst) {
  __shared__ ushort tile[32][33];
  const int bx = blockIdx.x & 31;   // d-tile
  const int by = blockIdx.x >> 5;   // k-tile
  const int lx = threadIdx.x & 31, ly = threadIdx.x >> 5;  // 32 x 8
#pragma unroll
  for (int i = 0; i < 32; i += 8)
    tile[ly + i][lx] = f2bf(src[(size_t)(by * 32 + ly + i) * H_ + bx * 32 + lx]);
  __syncthreads();
#pragma unroll
  for (int i = 0; i < 32; i += 8)
    dst[(size_t)(bx * 32 + ly + i) * H_ + by * 32 + lx] = tile[lx][ly + i];
}

// ---------------------------------------------------------------------------
// ctxp[m, d] = sum_k ctx[m, k] * WaT[d, k],  m = s*B+b.  f32 output.
__global__ __launch_bounds__(256) void k_ctxp(const ushort* __restrict__ ctx,
                                              const ushort* __restrict__ WaT,
                                              float* __restrict__ ctxp) {
  const int tid = threadIdx.x;
  const int wave = tid >> 6, lane = tid & 63;
  const int quad = lane >> 4, l16 = lane & 15;
  const int m0 = blockIdx.x * 64 + wave * 16;
  const int n0 = blockIdx.y * 64;
  const ushort* ar = ctx + (size_t)(m0 + l16) * H_;
  const int koff = quad * 8;
  f32x4 acc[4] = {};
  for (int k0 = 0; k0 < H_; k0 += 32) {
    int kk = k0 + koff;
    short8 a = *(const short8*)(ar + kk);
#pragma unroll
    for (int nt = 0; nt < 4; ++nt) {
      short8 b = *(const short8*)(WaT + (size_t)(n0 + nt * 16 + l16) * H_ + kk);
      acc[nt] = __builtin_amdgcn_mfma_f32_16x16x32_bf16(a, b, acc[nt], 0, 0, 0);
    }
  }
#pragma unroll
  for (int nt = 0; nt < 4; ++nt)
#pragma unroll
    for (int r = 0; r < 4; ++r)
      ctxp[(size_t)(m0 + quad * 4 + r) * H_ + n0 + nt * 16 + l16] = acc[nt][r];
}

// ---------------------------------------------------------------------------
__global__ __launch_bounds__(256) void k_init(const float* __restrict__ h0in,
                                              ushort* __restrict__ h0b,
                                              ushort* __restrict__ h1b,
                                              ushort* __restrict__ fdb,
                                              unsigned* __restrict__ flags) {
  int i = blockIdx.x * 256 + threadIdx.x;
  h0b[i] = f2bf(h0in[i]);
  h1b[i] = f2bf(h0in[BH + i]);
  fdb[i] = 0;
  if (blockIdx.x == 0) flags[threadIdx.x * 16] = 0;
}

// ---------------------------------------------------------------------------
// Grid barrier without cache-invalidating fences (see round-2 notes).
static __device__ __forceinline__ void grid_bar(unsigned* flags, unsigned gen) {
  __syncthreads();
  if (blockIdx.x == 0) {
    const int tid = threadIdx.x;
    if (tid > 0) {
      while (ld32_dev(&flags[tid * 16]) < gen) __builtin_amdgcn_s_sleep(4);
    }
    __syncthreads();
    if (tid == 0) st32_dev(&flags[0], gen);
    __syncthreads();
  } else {
    if (threadIdx.x == 0) {
      st32_dev(&flags[blockIdx.x * 16], gen);
      while (ld32_dev(&flags[0]) < gen) __builtin_amdgcn_s_sleep(4);
    }
    __syncthreads();
  }
  asm volatile("" ::: "memory");
}

// ---------------------------------------------------------------------------
struct FusedP {
  const ushort* inp;
  const ushort* Wih0; const ushort* Whh0;
  const ushort* Wih1; const ushort* Whh1;
  const ushort* Wout;
  const ushort* ctx;
  const float* ctxp;
  const float* bih0; const float* bhh0;
  const float* bih1; const float* bhh1;
  const float* c0in;
  ushort* h0b;   // (T_+1) rotated (B,H) bf16 buffers -- write-once
  ushort* h1b;   // (T_+1)
  ushort* fdb;   // (T_+1)
  ushort* cvb;   // (T_)
  float* outs; float* hF; float* cF; float* attns;
  unsigned* flags;
};

// Persistent kernel. LSTM weight slices (144.5 KB/block) live in LDS for all
// 64 steps -> phases 1-2 never touch L2/L3 for weights (was 37.8 MB/step of
// L2-miss thrash). Inter-phase data: write-once rotated buffers, sc1 stores.
__global__ __launch_bounds__(256, 1) void k_fused(FusedP p) {
  extern __shared__ ushort wlds[];          // [16*W0ROW] + [16*W1ROW]
  ushort* w0 = wlds;
  ushort* w1 = wlds + 16 * W0ROW;
  __shared__ float st[4][16][17];
  __shared__ float al[S_];
  const int blk = blockIdx.x;
  const int tid = threadIdx.x;
  const int wave = tid >> 6, lane = tid & 63;
  const int quad = lane >> 4, l16 = lane & 15;
  const int j0 = blk * 4;

  // ---- stage this block's weight slice into LDS (once) ----
  // row r (l16): packed-gate row n = (r>>2)*H + j0 + (r&3)
  for (int idx = tid; idx < 16 * 192; idx += 256) {   // Wih0: 1536 = 192*8
    int r = idx / 192, c = (idx % 192) * 8;
    int n = (r >> 2) * H_ + j0 + (r & 3);
    *(short8*)(w0 + r * W0ROW + c) =
        *(const short8*)(p.Wih0 + (size_t)n * (E_ + H_) + c);
  }
  for (int idx = tid; idx < 16 * 128; idx += 256) {   // Whh0: 1024 = 128*8
    int r = idx / 128, c = (idx % 128) * 8;
    int n = (r >> 2) * H_ + j0 + (r & 3);
    *(short8*)(w0 + r * W0ROW + (E_ + H_) + c) =
        *(const short8*)(p.Whh0 + (size_t)n * H_ + c);
  }
  for (int idx = tid; idx < 16 * 128; idx += 256) {   // Wih1
    int r = idx / 128, c = (idx % 128) * 8;
    int n = (r >> 2) * H_ + j0 + (r & 3);
    *(short8*)(w1 + r * W1ROW + c) =
        *(const short8*)(p.Wih1 + (size_t)n * H_ + c);
  }
  for (int idx = tid; idx < 16 * 128; idx += 256) {   // Whh1
    int r = idx / 128, c = (idx % 128) * 8;
    int n = (r >> 2) * H_ + j0 + (r & 3);
    *(short8*)(w1 + r * W1ROW + H_ + c) =
        *(const short8*)(p.Whh1 + (size_t)n * H_ + c);
  }
  __syncthreads();

  // per-thread fixed (b,j) for the gate tail; biases hoisted to registers
  const int own_b = 16 * wave + (lane & 15);
  const int own_j = j0 + (lane >> 4);
  const int own_idx = own_b * H_ + own_j;
  float c0reg = p.c0in[own_idx];
  float c1reg = p.c0in[BH + own_idx];
  const float b0i = p.bih0[own_j]          + p.bhh0[own_j];
  const float b0f = p.bih0[H_ + own_j]     + p.bhh0[H_ + own_j];
  const float b0g = p.bih0[2 * H_ + own_j] + p.bhh0[2 * H_ + own_j];
  const float b0o = p.bih0[3 * H_ + own_j] + p.bhh0[3 * H_ + own_j];
  const float b1i = p.bih1[own_j]          + p.bhh1[own_j];
  const float b1f = p.bih1[H_ + own_j]     + p.bhh1[H_ + own_j];
  const float b1g = p.bih1[2 * H_ + own_j] + p.bhh1[2 * H_ + own_j];
  const float b1o = p.bih1[3 * H_ + own_j] + p.bhh1[3 * H_ + own_j];

  const ushort* w0r = w0 + l16 * W0ROW;   // B-fragment row for MFMA
  const ushort* w1r = w1 + l16 * W1ROW;
  const int koff = quad * 8;

  unsigned gen = 0;

  for (int t = 0; t < T_; ++t) {
    const ushort* h0prev = p.h0b + (size_t)t * BH;
    ushort* h0new       = p.h0b + (size_t)(t + 1) * BH;
    const ushort* h1prev = p.h1b + (size_t)t * BH;
    ushort* h1new       = p.h1b + (size_t)(t + 1) * BH;
    const ushort* feedr  = p.fdb + (size_t)t * BH;
    ushort* feedw       = p.fdb + (size_t)(t + 1) * BH;
    ushort* cv          = p.cvb + (size_t)t * BH;
    const int last = (t == T_ - 1);

    // ---- phase 1: LSTM layer 0 (weights from LDS) ----
    {
      const int arow = 16 * wave + l16;
      const ushort* er = p.inp + ((size_t)t * B_ + arow) * E_;
      const ushort* fr = feedr + (size_t)arow * H_;
      const ushort* hr = h0prev + (size_t)arow * H_;
      f32x4 acc = {};
      for (int k0 = 0; k0 < E_ + 2 * H_; k0 += 32) {
        int kk = k0 + koff;
        short8 a;
        if (kk < E_)            a = *(const short8*)(er + kk);
        else if (kk < E_ + H_)  a = *(const short8*)(fr + (kk - E_));
        else                    a = *(const short8*)(hr + (kk - E_ - H_));
        short8 b = *(const short8*)(w0r + kk);
        acc = __builtin_amdgcn_mfma_f32_16x16x32_bf16(a, b, acc, 0, 0, 0);
      }
#pragma unroll
      for (int r = 0; r < 4; ++r) st[wave][quad * 4 + r][l16] = acc[r];
      const int bl = lane & 15, jj = lane >> 4;
      const int b = own_b;
      float gi = st[wave][bl][0 + jj]  + b0i;
      float gf = st[wave][bl][4 + jj]  + b0f;
      float gg = st[wave][bl][8 + jj]  + b0g;
      float go = st[wave][bl][12 + jj] + b0o;
      float cn = sigm(gf) * c0reg + sigm(gi) * tanhf(gg);
      float hn = sigm(go) * tanhf(cn);
      c0reg = cn;
      if (last) { p.hF[own_idx] = hn; p.cF[own_idx] = cn; }
      unsigned u = f2bf(hn);
      unsigned up = __shfl_down(u, 16);
      if (!(jj & 1))
        st32_dev((unsigned*)h0new + b * (H_ / 2) + blk * 2 + (jj >> 1),
                 u | (up << 16));
    }
    grid_bar(p.flags, ++gen);

    // ---- phase 2: LSTM layer 1 (weights from LDS) ----
    {
      const int arow = 16 * wave + l16;
      const ushort* xr = h0new + (size_t)arow * H_;
      const ushort* hr = h1prev + (size_t)arow * H_;
      f32x4 acc = {};
      for (int k0 = 0; k0 < 2 * H_; k0 += 32) {
        int kk = k0 + koff;
        short8 a = (kk < H_) ? *(const short8*)(xr + kk)
                             : *(const short8*)(hr + (kk - H_));
        short8 b = *(const short8*)(w1r + kk);
        acc = __builtin_amdgcn_mfma_f32_16x16x32_bf16(a, b, acc, 0, 0, 0);
      }
#pragma unroll
      for (int r = 0; r < 4; ++r) st[wave][quad * 4 + r][l16] = acc[r];
      const int bl = lane & 15, jj = lane >> 4;
      const int b = own_b;
      float gi = st[wave][bl][0 + jj]  + b1i;
      float gf = st[wave][bl][4 + jj]  + b1f;
      float gg = st[wave][bl][8 + jj]  + b1g;
      float go = st[wave][bl][12 + jj] + b1o;
      float cn = sigm(gf) * c1reg + sigm(gi) * tanhf(gg);
      float hn = sigm(go) * tanhf(cn);
      c1reg = cn;
      if (last) { p.hF[BH + own_idx] = hn; p.cF[BH + own_idx] = cn; }
      unsigned u = f2bf(hn);
      unsigned up = __shfl_down(u, 16);
      if (!(jj & 1))
        st32_dev((unsigned*)h1new + b * (H_ / 2) + blk * 2 + (jj >> 1),
                 u | (up << 16));
    }
    grid_bar(p.flags, ++gen);

    // ---- phase 3: attention (score + softmax + cvec), blocks 0..63 ----
    if (blk < B_) {
      const int b = blk;
      float qreg[16];
#pragma unroll
      for (int c = 0; c < 4; ++c) {
        short4v v = *(const short4v*)(h1new + (size_t)b * H_ + c * 256 + lane * 4);
#pragma unroll
        for (int j2 = 0; j2 < 4; ++j2) qreg[c * 4 + j2] = bf2f((ushort)v[j2]);
      }
#pragma unroll 4
      for (int i = 0; i < 32; ++i) {
        const int s = wave * 32 + i;
        const float* row = p.ctxp + ((size_t)s * B_ + b) * H_;
        float pr = 0.f;
#pragma unroll
        for (int c = 0; c < 4; ++c) {
          f32x4 v = *(const f32x4*)(row + c * 256 + lane * 4);
          pr += v[0] * qreg[c * 4 + 0] + v[1] * qreg[c * 4 + 1] +
                v[2] * qreg[c * 4 + 2] + v[3] * qreg[c * 4 + 3];
        }
#pragma unroll
        for (int off = 32; off; off >>= 1) pr += __shfl_down(pr, off);
        if (lane == 0) al[s] = pr;
      }
      __syncthreads();
      if (wave == 0) {
        float m = fmaxf(al[lane], al[lane + 64]);
#pragma unroll
        for (int off = 32; off; off >>= 1) m = fmaxf(m, __shfl_down(m, off));
        m = __shfl(m, 0);
        float e0 = expf(al[lane] - m), e1 = expf(al[lane + 64] - m);
        float s2 = e0 + e1;
#pragma unroll
        for (int off = 32; off; off >>= 1) s2 += __shfl_down(s2, off);
        s2 = __shfl(s2, 0);
        float inv = 1.f / s2;
        al[lane] = e0 * inv;
        al[lane + 64] = e1 * inv;
      }
      __syncthreads();
      if (tid < S_) p.attns[((size_t)t * B_ + b) * S_ + tid] = al[tid];
      {
        const int d0 = tid * 4;
        const ushort* cb = p.ctx + (size_t)b * H_ + d0;
        float a0 = 0.f, a1 = 0.f, a2 = 0.f, a3 = 0.f;
#pragma unroll 4
        for (int s = 0; s < S_; ++s) {
          short4v v = *(const short4v*)(cb + (size_t)s * B_ * H_);
          float w = al[s];
          a0 += w * bf2f((ushort)v[0]);
          a1 += w * bf2f((ushort)v[1]);
          a2 += w * bf2f((ushort)v[2]);
          a3 += w * bf2f((ushort)v[3]);
        }
        unsigned lo = (unsigned)f2bf(a0) | ((unsigned)f2bf(a1) << 16);
        unsigned hi = (unsigned)f2bf(a2) | ((unsigned)f2bf(a3) << 16);
        st64_dev((unsigned long long*)cv + b * (H_ / 4) + tid,
                 (unsigned long long)lo | ((unsigned long long)hi << 32));
      }
    }
    grid_bar(p.flags, ++gen);

    // ---- phase 4: output projection, blocks 0..63 (16 j-cols each) ----
    if (blk < 64) {
      const int pj0 = blk * 16;
      const int arow = 16 * wave + l16;
      const ushort* cr = cv + (size_t)arow * H_;
      const ushort* hr2 = h1new + (size_t)arow * H_;
      const ushort* wr = p.Wout + (size_t)(pj0 + l16) * (2 * H_);
      f32x4 acc = {};
      for (int k0 = 0; k0 < 2 * H_; k0 += 32) {
        int kk = k0 + koff;
        short8 a = (kk < H_) ? *(const short8*)(cr + kk)
                             : *(const short8*)(hr2 + (kk - H_));
        short8 b = *(const short8*)(wr + kk);
        acc = __builtin_amdgcn_mfma_f32_16x16x32_bf16(a, b, acc, 0, 0, 0);
      }
      const int j = pj0 + l16;
#pragma unroll
      for (int r = 0; r < 4; ++r) {
        int b = 16 * wave + quad * 4 + r;
        float v = tanhf(acc[r]);
        p.outs[(size_t)t * B_ * H_ + b * H_ + j] = v;
        unsigned u = f2bf(v);
        unsigned up = __shfl_down(u, 1);
        if (!(l16 & 1))
          st32_dev((unsigned*)feedw + b * (H_ / 2) + blk * 8 + (l16 >> 1),
                   u | (up << 16));
      }
    }
    grid_bar(p.flags, ++gen);
  }
}

// ---------------------------------------------------------------------------
extern "C" void kernel_launch(void* const* d_in, const int* in_sizes, int n_in,
                              void* d_out, int out_size, void* d_ws, size_t ws_size,
                              hipStream_t stream) {
  const float* inpf  = (const float*)d_in[0];
  const float* ctxf  = (const float*)d_in[1];
  const float* h0in  = (const float*)d_in[2];
  const float* c0in  = (const float*)d_in[3];
  const float* Wih0f = (const float*)d_in[4];
  const float* bih0  = (const float*)d_in[5];
  const float* Whh0f = (const float*)d_in[6];
  const float* bhh0  = (const float*)d_in[7];
  const float* Wih1f = (const float*)d_in[8];
  const float* bih1  = (const float*)d_in[9];
  const float* Whh1f = (const float*)d_in[10];
  const float* bhh1  = (const float*)d_in[11];
  const float* Waf   = (const float*)d_in[12];
  const float* Woutf = (const float*)d_in[13];

  float* out = (float*)d_out;
  float* outs  = out;                              // (T,B,H)
  float* hF    = out + (size_t)T_ * B_ * H_;       // (2,B,H)
  float* cF    = hF + 2 * BH;                      // (2,B,H)
  float* attns = cF + 2 * BH;                      // (T,B,S)

  char* p = (char*)d_ws;
  auto take = [&](size_t bytes) -> char* {
    char* q = p;
    p += (bytes + 255) & ~(size_t)255;
    return q;
  };
  ushort* h0b  = (ushort*)take((size_t)(T_ + 1) * BH * 2);
  ushort* h1b  = (ushort*)take((size_t)(T_ + 1) * BH * 2);
  ushort* fdb  = (ushort*)take((size_t)(T_ + 1) * BH * 2);
  ushort* cvb  = (ushort*)take((size_t)T_ * BH * 2);
  unsigned* flags = (unsigned*)take(256 * 16 * sizeof(unsigned));
  ushort* WaT  = (ushort*)take((size_t)H_ * H_ * 2);
  float* ctxp  = (float*)take((size_t)S_ * B_ * H_ * 4);

  struct { const float* src; int n; } cv[7] = {
    {Wih0f, 4 * H_ * (E_ + H_)}, {Whh0f, 4 * H_ * H_},
    {Wih1f, 4 * H_ * H_},        {Whh1f, 4 * H_ * H_},
    {Woutf, 2 * H_ * H_},
    {inpf,  T_ * B_ * E_},       {ctxf,  S_ * B_ * H_},
  };
  ushort* cb[7];
  for (int i = 0; i < 7; ++i) {
    cb[i] = (ushort*)take((size_t)cv[i].n * 2);
    int n4 = cv[i].n / 4;
    k_cvt<<<(n4 + 255) / 256, 256, 0, stream>>>(cv[i].src, cb[i], n4);
  }
  const ushort *Wih0 = cb[0], *Whh0 = cb[1], *Wih1 = cb[2], *Whh1 = cb[3],
               *Wout = cb[4], *inp = cb[5], *ctx = cb[6];

  k_cvtT<<<(H_ / 32) * (H_ / 32), 256, 0, stream>>>(Waf, WaT);
  k_ctxp<<<dim3((S_ * B_) / 64, H_ / 64), 256, 0, stream>>>(ctx, WaT, ctxp);
  k_init<<<BH / 256, 256, 0, stream>>>(h0in, h0b, h1b, fdb, flags);

  static int smem_set = 0;
  if (!smem_set) {
    hipFuncSetAttribute((const void*)k_fused,
                        hipFuncAttributeMaxDynamicSharedMemorySize, SMEM_BYTES);
    smem_set = 1;
  }

  FusedP fp;
  fp.inp = inp; fp.Wih0 = Wih0; fp.Whh0 = Whh0; fp.Wih1 = Wih1; fp.Whh1 = Whh1;
  fp.Wout = Wout; fp.ctx = ctx; fp.ctxp = ctxp;
  fp.bih0 = bih0; fp.bhh0 = bhh0; fp.bih1 = bih1; fp.bhh1 = bhh1;
  fp.c0in = c0in;
  fp.h0b = h0b; fp.h1b = h1b; fp.fdb = fdb; fp.cvb = cvb;
  fp.outs = outs; fp.hF = hF; fp.cF = cF; fp.attns = attns;
  fp.flags = flags;
  void* kargs[] = {(void*)&fp};
  hipLaunchCooperativeKernel(k_fused, dim3(256), dim3(256), kargs,
                             (unsigned)SMEM_BYTES, stream);
}

// Round 5
// 5336.389 us; speedup vs baseline: 1.6778x; 1.0126x over previous
//
#include <hip/hip_runtime.h>

#define T_ 64
#define B_ 64
#define S_ 128
#define E_ 512
#define H_ 1024
#define BH (B_ * H_)

// LDS weight slice geometry (bf16 elements), +8 pad => row stride = 4 banks
#define W0ROW (E_ + 2 * H_ + 8)   // 2568
#define W1ROW (2 * H_ + 8)        // 2056
#define SMEM_BYTES ((16 * W0ROW + 16 * W1ROW) * 2)  // 147968 B

typedef __attribute__((ext_vector_type(8))) short short8;
typedef __attribute__((ext_vector_type(4))) short short4v;
typedef __attribute__((ext_vector_type(4))) float f32x4;

static __device__ __forceinline__ float bf2f(ushort u) {
  union { float f; unsigned u; } x; x.u = ((unsigned)u) << 16; return x.f;
}
static __device__ __forceinline__ ushort f2bf(float f) {
  union { float f; unsigned u; } x; x.f = f;
  unsigned r = 0x7FFFu + ((x.u >> 16) & 1u);
  return (ushort)((x.u + r) >> 16);
}
static __device__ __forceinline__ float sigm(float x) {
  return 1.f / (1.f + expf(-x));
}

// device-scope (sc1) relaxed atomics: write-through to the coherence point.
static __device__ __forceinline__ void st32_dev(unsigned* p, unsigned v) {
  __hip_atomic_store(p, v, __ATOMIC_RELAXED, __HIP_MEMORY_SCOPE_AGENT);
}
static __device__ __forceinline__ unsigned ld32_dev(const unsigned* p) {
  return __hip_atomic_load(p, __ATOMIC_RELAXED, __HIP_MEMORY_SCOPE_AGENT);
}
static __device__ __forceinline__ void stf_dev(float* p, float v) {
  union { float f; unsigned u; } x; x.f = v;
  st32_dev((unsigned*)p, x.u);
}

// ---------------------------------------------------------------------------
__global__ __launch_bounds__(256) void k_cvt(const float* __restrict__ src,
                                             ushort* __restrict__ dst, int n4) {
  int i = blockIdx.x * 256 + threadIdx.x;
  if (i >= n4) return;
  f32x4 v = ((const f32x4*)src)[i];
  short4v o;
  o[0] = (short)f2bf(v[0]); o[1] = (short)f2bf(v[1]);
  o[2] = (short)f2bf(v[2]); o[3] = (short)f2bf(v[3]);
  ((short4v*)dst)[i] = o;
}

// ---------------------------------------------------------------------------
// f32 (H,H) [k][d]  ->  bf16 (H,H) [d][k]  (transpose + convert, LDS tiled)
__global__ __launch_bounds__(256) void k_cvtT(const float* __restrict__ src,
                                              ushort* __restrict__ dst) {
  __shared__ ushort tile[32][33];
  const int bx = blockIdx.x & 31;   // d-tile
  const int by = blockIdx.x >> 5;   // k-tile
  const int lx = threadIdx.x & 31, ly = threadIdx.x >> 5;  // 32 x 8
#pragma unroll
  for (int i = 0; i < 32; i += 8)
    tile[ly + i][lx] = f2bf(src[(size_t)(by * 32 + ly + i) * H_ + bx * 32 + lx]);
  __syncthreads();
#pragma unroll
  for (int i = 0; i < 32; i += 8)
    dst[(size_t)(bx * 32 + ly + i) * H_ + by * 32 + lx] = tile[lx][ly + i];
}

// ---------------------------------------------------------------------------
// ctxp[m, d] = sum_k ctx[m, k] * WaT[d, k],  m = s*B+b.  bf16 output.
__global__ __launch_bounds__(256) void k_ctxp(const ushort* __restrict__ ctx,
                                              const ushort* __restrict__ WaT,
                                              ushort* __restrict__ ctxp) {
  const int tid = threadIdx.x;
  const int wave = tid >> 6, lane = tid & 63;
  const int quad = lane >> 4, l16 = lane & 15;
  const int m0 = blockIdx.x * 64 + wave * 16;
  const int n0 = blockIdx.y * 64;
  const ushort* ar = ctx + (size_t)(m0 + l16) * H_;
  const int koff = quad * 8;
  f32x4 acc[4] = {};
  for (int k0 = 0; k0 < H_; k0 += 32) {
    int kk = k0 + koff;
    short8 a = *(const short8*)(ar + kk);
#pragma unroll
    for (int nt = 0; nt < 4; ++nt) {
      short8 b = *(const short8*)(WaT + (size_t)(n0 + nt * 16 + l16) * H_ + kk);
      acc[nt] = __builtin_amdgcn_mfma_f32_16x16x32_bf16(a, b, acc[nt], 0, 0, 0);
    }
  }
#pragma unroll
  for (int nt = 0; nt < 4; ++nt)
#pragma unroll
    for (int r = 0; r < 4; ++r)
      ctxp[(size_t)(m0 + quad * 4 + r) * H_ + n0 + nt * 16 + l16] =
          f2bf(acc[nt][r]);
}

// ---------------------------------------------------------------------------
__global__ __launch_bounds__(256) void k_init(const float* __restrict__ h0in,
                                              ushort* __restrict__ h0b,
                                              ushort* __restrict__ h1b,
                                              ushort* __restrict__ fdb,
                                              unsigned* __restrict__ flags) {
  int i = blockIdx.x * 256 + threadIdx.x;
  h0b[i] = f2bf(h0in[i]);
  h1b[i] = f2bf(h0in[BH + i]);
  fdb[i] = 0;
  if (blockIdx.x == 0) flags[threadIdx.x * 16] = 0;
}

// ---------------------------------------------------------------------------
// Grid barrier (round-3 proven): block 0 collects per-block arrival flags,
// broadcasts via flags[0]. sc1 stores reach the coherence point;
// __syncthreads drains vmcnt. No cache-invalidating fences.
static __device__ __forceinline__ void grid_bar(unsigned* flags, unsigned gen) {
  __syncthreads();
  if (blockIdx.x == 0) {
    const int tid = threadIdx.x;
    if (tid > 0) {
      while (ld32_dev(&flags[tid * 16]) < gen) __builtin_amdgcn_s_sleep(4);
    }
    __syncthreads();
    if (tid == 0) st32_dev(&flags[0], gen);
    __syncthreads();
  } else {
    if (threadIdx.x == 0) {
      st32_dev(&flags[blockIdx.x * 16], gen);
      while (ld32_dev(&flags[0]) < gen) __builtin_amdgcn_s_sleep(4);
    }
    __syncthreads();
  }
  asm volatile("" ::: "memory");
}

// ---------------------------------------------------------------------------
struct FusedP {
  const ushort* inp;
  const ushort* Wih0; const ushort* Whh0;
  const ushort* Wih1; const ushort* Whh1;
  const ushort* Wout;
  const ushort* ctx;
  const ushort* ctxp;    // bf16 (S,B,H)
  const float* bih0; const float* bhh0;
  const float* bih1; const float* bhh1;
  const float* c0in;
  ushort* h0b;   // (T_+1) rotated (B,H) bf16 buffers -- write-once
  ushort* h1b;   // (T_+1)
  ushort* fdb;   // (T_+1)
  ushort* cvb;   // (T_)
  float* psb;    // (T_) rotated (B,S,4) f32 partial scores -- write-once
  float* outs; float* hF; float* cF; float* attns;
  unsigned* flags;
};

// Persistent kernel, 5 barriers/step. LSTM weights LDS-resident.
// Attention spread over all 256 blocks as (b, d-quarter); ctxp bf16 so the
// per-XCD phase-3 slices (~4-5 MB) stay mostly L2-resident across steps.
__global__ __launch_bounds__(256, 1) void k_fused(FusedP p) {
  extern __shared__ ushort wlds[];          // [16*W0ROW] + [16*W1ROW]
  ushort* w0 = wlds;
  ushort* w1 = wlds + 16 * W0ROW;
  __shared__ float st[4][16][17];
  __shared__ float al[S_];
  __shared__ float red[4][256];
  const int blk = blockIdx.x;
  const int tid = threadIdx.x;
  const int wave = tid >> 6, lane = tid & 63;
  const int quad = lane >> 4, l16 = lane & 15;
  const int j0 = blk * 4;

  // ---- stage this block's weight slice into LDS (once) ----
  for (int idx = tid; idx < 16 * 192; idx += 256) {   // Wih0
    int r = idx / 192, c = (idx % 192) * 8;
    int n = (r >> 2) * H_ + j0 + (r & 3);
    *(short8*)(w0 + r * W0ROW + c) =
        *(const short8*)(p.Wih0 + (size_t)n * (E_ + H_) + c);
  }
  for (int idx = tid; idx < 16 * 128; idx += 256) {   // Whh0
    int r = idx / 128, c = (idx % 128) * 8;
    int n = (r >> 2) * H_ + j0 + (r & 3);
    *(short8*)(w0 + r * W0ROW + (E_ + H_) + c) =
        *(const short8*)(p.Whh0 + (size_t)n * H_ + c);
  }
  for (int idx = tid; idx < 16 * 128; idx += 256) {   // Wih1
    int r = idx / 128, c = (idx % 128) * 8;
    int n = (r >> 2) * H_ + j0 + (r & 3);
    *(short8*)(w1 + r * W1ROW + c) =
        *(const short8*)(p.Wih1 + (size_t)n * H_ + c);
  }
  for (int idx = tid; idx < 16 * 128; idx += 256) {   // Whh1
    int r = idx / 128, c = (idx % 128) * 8;
    int n = (r >> 2) * H_ + j0 + (r & 3);
    *(short8*)(w1 + r * W1ROW + H_ + c) =
        *(const short8*)(p.Whh1 + (size_t)n * H_ + c);
  }
  __syncthreads();

  // per-thread fixed (b,j); biases hoisted to registers
  const int own_b = 16 * wave + (lane & 15);
  const int own_j = j0 + (lane >> 4);
  const int own_idx = own_b * H_ + own_j;
  float c0reg = p.c0in[own_idx];
  float c1reg = p.c0in[BH + own_idx];
  const float b0i = p.bih0[own_j]          + p.bhh0[own_j];
  const float b0f = p.bih0[H_ + own_j]     + p.bhh0[H_ + own_j];
  const float b0g = p.bih0[2 * H_ + own_j] + p.bhh0[2 * H_ + own_j];
  const float b0o = p.bih0[3 * H_ + own_j] + p.bhh0[3 * H_ + own_j];
  const float b1i = p.bih1[own_j]          + p.bhh1[own_j];
  const float b1f = p.bih1[H_ + own_j]     + p.bhh1[H_ + own_j];
  const float b1g = p.bih1[2 * H_ + own_j] + p.bhh1[2 * H_ + own_j];
  const float b1o = p.bih1[3 * H_ + own_j] + p.bhh1[3 * H_ + own_j];

  const ushort* w0r = w0 + l16 * W0ROW;   // B-fragment row for MFMA
  const ushort* w1r = w1 + l16 * W1ROW;
  const int koff = quad * 8;

  // attention decomposition: this block owns (b3, d-quarter dq)
  const int b3 = blk >> 2, dq = blk & 3;
  const int d0 = dq * 256;

  unsigned gen = 0;

  for (int t = 0; t < T_; ++t) {
    const ushort* h0prev = p.h0b + (size_t)t * BH;
    ushort* h0new       = p.h0b + (size_t)(t + 1) * BH;
    const ushort* h1prev = p.h1b + (size_t)t * BH;
    ushort* h1new       = p.h1b + (size_t)(t + 1) * BH;
    const ushort* feedr  = p.fdb + (size_t)t * BH;
    ushort* feedw       = p.fdb + (size_t)(t + 1) * BH;
    ushort* cv          = p.cvb + (size_t)t * BH;
    float* pst          = p.psb + (size_t)t * B_ * S_ * 4;
    const int last = (t == T_ - 1);

    // ---- phase 1: LSTM layer 0 (weights from LDS) ----
    {
      const int arow = 16 * wave + l16;
      const ushort* er = p.inp + ((size_t)t * B_ + arow) * E_;
      const ushort* fr = feedr + (size_t)arow * H_;
      const ushort* hr = h0prev + (size_t)arow * H_;
      f32x4 acc = {};
      for (int k0 = 0; k0 < E_ + 2 * H_; k0 += 32) {
        int kk = k0 + koff;
        short8 a;
        if (kk < E_)            a = *(const short8*)(er + kk);
        else if (kk < E_ + H_)  a = *(const short8*)(fr + (kk - E_));
        else                    a = *(const short8*)(hr + (kk - E_ - H_));
        short8 b = *(const short8*)(w0r + kk);
        acc = __builtin_amdgcn_mfma_f32_16x16x32_bf16(a, b, acc, 0, 0, 0);
      }
#pragma unroll
      for (int r = 0; r < 4; ++r) st[wave][quad * 4 + r][l16] = acc[r];
      const int bl = lane & 15, jj = lane >> 4;
      float gi = st[wave][bl][0 + jj]  + b0i;
      float gf = st[wave][bl][4 + jj]  + b0f;
      float gg = st[wave][bl][8 + jj]  + b0g;
      float go = st[wave][bl][12 + jj] + b0o;
      float cn = sigm(gf) * c0reg + sigm(gi) * tanhf(gg);
      float hn = sigm(go) * tanhf(cn);
      c0reg = cn;
      if (last) { p.hF[own_idx] = hn; p.cF[own_idx] = cn; }
      unsigned u = f2bf(hn);
      unsigned up = __shfl_down(u, 16);
      if (!(jj & 1))
        st32_dev((unsigned*)h0new + own_b * (H_ / 2) + blk * 2 + (jj >> 1),
                 u | (up << 16));
    }
    grid_bar(p.flags, ++gen);

    // ---- phase 2: LSTM layer 1 (weights from LDS) ----
    {
      const int arow = 16 * wave + l16;
      const ushort* xr = h0new + (size_t)arow * H_;
      const ushort* hr = h1prev + (size_t)arow * H_;
      f32x4 acc = {};
      for (int k0 = 0; k0 < 2 * H_; k0 += 32) {
        int kk = k0 + koff;
        short8 a = (kk < H_) ? *(const short8*)(xr + kk)
                             : *(const short8*)(hr + (kk - H_));
        short8 b = *(const short8*)(w1r + kk);
        acc = __builtin_amdgcn_mfma_f32_16x16x32_bf16(a, b, acc, 0, 0, 0);
      }
#pragma unroll
      for (int r = 0; r < 4; ++r) st[wave][quad * 4 + r][l16] = acc[r];
      const int bl = lane & 15, jj = lane >> 4;
      float gi = st[wave][bl][0 + jj]  + b1i;
      float gf = st[wave][bl][4 + jj]  + b1f;
      float gg = st[wave][bl][8 + jj]  + b1g;
      float go = st[wave][bl][12 + jj] + b1o;
      float cn = sigm(gf) * c1reg + sigm(gi) * tanhf(gg);
      float hn = sigm(go) * tanhf(cn);
      c1reg = cn;
      if (last) { p.hF[BH + own_idx] = hn; p.cF[BH + own_idx] = cn; }
      unsigned u = f2bf(hn);
      unsigned up = __shfl_down(u, 16);
      if (!(jj & 1))
        st32_dev((unsigned*)h1new + own_b * (H_ / 2) + blk * 2 + (jj >> 1),
                 u | (up << 16));
    }
    grid_bar(p.flags, ++gen);

    // ---- phase 3a: partial scores over this block's d-quarter ----
    {
      short4v qv = *(const short4v*)(h1new + (size_t)b3 * H_ + d0 + lane * 4);
      float q0 = bf2f((ushort)qv[0]), q1 = bf2f((ushort)qv[1]);
      float q2 = bf2f((ushort)qv[2]), q3 = bf2f((ushort)qv[3]);
#pragma unroll 4
      for (int i = 0; i < 32; ++i) {
        const int s = wave * 32 + i;
        short4v v = *(const short4v*)(p.ctxp + ((size_t)s * B_ + b3) * H_ +
                                      d0 + lane * 4);
        float pr = bf2f((ushort)v[0]) * q0 + bf2f((ushort)v[1]) * q1 +
                   bf2f((ushort)v[2]) * q2 + bf2f((ushort)v[3]) * q3;
#pragma unroll
        for (int off = 32; off; off >>= 1) pr += __shfl_down(pr, off);
        if (lane == 0) stf_dev(pst + (b3 * S_ + s) * 4 + dq, pr);
      }
    }
    grid_bar(p.flags, ++gen);

    // ---- phase 3b: reduce + softmax + cvec d-quarter ----
    {
      if (tid < S_) {
        f32x4 ps = *(const f32x4*)(pst + (b3 * S_ + tid) * 4);
        al[tid] = ps[0] + ps[1] + ps[2] + ps[3];
      }
      __syncthreads();
      if (wave == 0) {
        float m = fmaxf(al[lane], al[lane + 64]);
#pragma unroll
        for (int off = 32; off; off >>= 1) m = fmaxf(m, __shfl_down(m, off));
        m = __shfl(m, 0);
        float e0 = expf(al[lane] - m), e1 = expf(al[lane + 64] - m);
        float s2 = e0 + e1;
#pragma unroll
        for (int off = 32; off; off >>= 1) s2 += __shfl_down(s2, off);
        s2 = __shfl(s2, 0);
        float inv = 1.f / s2;
        al[lane] = e0 * inv;
        al[lane + 64] = e1 * inv;
      }
      __syncthreads();
      if (dq == 0 && tid < S_)
        p.attns[((size_t)t * B_ + b3) * S_ + tid] = al[tid];
      // cvec over d-quarter: wave w covers s in [32w,32w+32), 4 d per lane
      float a0 = 0.f, a1 = 0.f, a2 = 0.f, a3 = 0.f;
#pragma unroll 4
      for (int i = 0; i < 32; ++i) {
        const int s = wave * 32 + i;
        short4v v = *(const short4v*)(p.ctx + ((size_t)s * B_ + b3) * H_ +
                                      d0 + lane * 4);
        float w = al[s];
        a0 += w * bf2f((ushort)v[0]);
        a1 += w * bf2f((ushort)v[1]);
        a2 += w * bf2f((ushort)v[2]);
        a3 += w * bf2f((ushort)v[3]);
      }
      red[wave][lane * 4 + 0] = a0;
      red[wave][lane * 4 + 1] = a1;
      red[wave][lane * 4 + 2] = a2;
      red[wave][lane * 4 + 3] = a3;
      __syncthreads();
      float val = red[0][tid] + red[1][tid] + red[2][tid] + red[3][tid];
      unsigned u = f2bf(val);
      unsigned up = __shfl_down(u, 1);
      if (!(tid & 1))
        st32_dev((unsigned*)cv + (b3 * H_ + d0 + tid) / 2, u | (up << 16));
    }
    grid_bar(p.flags, ++gen);

    // ---- phase 4: output projection, blocks 0..63 (16 j-cols each) ----
    if (blk < 64) {
      const int pj0 = blk * 16;
      const int arow = 16 * wave + l16;
      const ushort* cr = cv + (size_t)arow * H_;
      const ushort* hr2 = h1new + (size_t)arow * H_;
      const ushort* wr = p.Wout + (size_t)(pj0 + l16) * (2 * H_);
      f32x4 acc = {};
      for (int k0 = 0; k0 < 2 * H_; k0 += 32) {
        int kk = k0 + koff;
        short8 a = (kk < H_) ? *(const short8*)(cr + kk)
                             : *(const short8*)(hr2 + (kk - H_));
        short8 b = *(const short8*)(wr + kk);
        acc = __builtin_amdgcn_mfma_f32_16x16x32_bf16(a, b, acc, 0, 0, 0);
      }
      const int j = pj0 + l16;
#pragma unroll
      for (int r = 0; r < 4; ++r) {
        int b = 16 * wave + quad * 4 + r;
        float v = tanhf(acc[r]);
        p.outs[(size_t)t * B_ * H_ + b * H_ + j] = v;
        unsigned u = f2bf(v);
        unsigned up = __shfl_down(u, 1);
        if (!(l16 & 1))
          st32_dev((unsigned*)feedw + b * (H_ / 2) + blk * 8 + (l16 >> 1),
                   u | (up << 16));
      }
    }
    grid_bar(p.flags, ++gen);
  }
}

// ---------------------------------------------------------------------------
extern "C" void kernel_launch(void* const* d_in, const int* in_sizes, int n_in,
                              void* d_out, int out_size, void* d_ws, size_t ws_size,
                              hipStream_t stream) {
  const float* inpf  = (const float*)d_in[0];
  const float* ctxf  = (const float*)d_in[1];
  const float* h0in  = (const float*)d_in[2];
  const float* c0in  = (const float*)d_in[3];
  const float* Wih0f = (const float*)d_in[4];
  const float* bih0  = (const float*)d_in[5];
  const float* Whh0f = (const float*)d_in[6];
  const float* bhh0  = (const float*)d_in[7];
  const float* Wih1f = (const float*)d_in[8];
  const float* bih1  = (const float*)d_in[9];
  const float* Whh1f = (const float*)d_in[10];
  const float* bhh1  = (const float*)d_in[11];
  const float* Waf   = (const float*)d_in[12];
  const float* Woutf = (const float*)d_in[13];

  float* out = (float*)d_out;
  float* outs  = out;                              // (T,B,H)
  float* hF    = out + (size_t)T_ * B_ * H_;       // (2,B,H)
  float* cF    = hF + 2 * BH;                      // (2,B,H)
  float* attns = cF + 2 * BH;                      // (T,B,S)

  char* p = (char*)d_ws;
  auto take = [&](size_t bytes) -> char* {
    char* q = p;
    p += (bytes + 255) & ~(size_t)255;
    return q;
  };
  ushort* h0b  = (ushort*)take((size_t)(T_ + 1) * BH * 2);
  ushort* h1b  = (ushort*)take((size_t)(T_ + 1) * BH * 2);
  ushort* fdb  = (ushort*)take((size_t)(T_ + 1) * BH * 2);
  ushort* cvb  = (ushort*)take((size_t)T_ * BH * 2);
  float* psb   = (float*)take((size_t)T_ * B_ * S_ * 4 * 4);
  unsigned* flags = (unsigned*)take(256 * 16 * sizeof(unsigned));
  ushort* WaT  = (ushort*)take((size_t)H_ * H_ * 2);
  ushort* ctxp = (ushort*)take((size_t)S_ * B_ * H_ * 2);

  struct { const float* src; int n; } cv[7] = {
    {Wih0f, 4 * H_ * (E_ + H_)}, {Whh0f, 4 * H_ * H_},
    {Wih1f, 4 * H_ * H_},        {Whh1f, 4 * H_ * H_},
    {Woutf, 2 * H_ * H_},
    {inpf,  T_ * B_ * E_},       {ctxf,  S_ * B_ * H_},
  };
  ushort* cb[7];
  for (int i = 0; i < 7; ++i) {
    cb[i] = (ushort*)take((size_t)cv[i].n * 2);
    int n4 = cv[i].n / 4;
    k_cvt<<<(n4 + 255) / 256, 256, 0, stream>>>(cv[i].src, cb[i], n4);
  }
  const ushort *Wih0 = cb[0], *Whh0 = cb[1], *Wih1 = cb[2], *Whh1 = cb[3],
               *Wout = cb[4], *inp = cb[5], *ctx = cb[6];

  k_cvtT<<<(H_ / 32) * (H_ / 32), 256, 0, stream>>>(Waf, WaT);
  k_ctxp<<<dim3((S_ * B_) / 64, H_ / 64), 256, 0, stream>>>(ctx, WaT, ctxp);
  k_init<<<BH / 256, 256, 0, stream>>>(h0in, h0b, h1b, fdb, flags);

  static int smem_set = 0;
  if (!smem_set) {
    hipFuncSetAttribute((const void*)k_fused,
                        hipFuncAttributeMaxDynamicSharedMemorySize, SMEM_BYTES);
    smem_set = 1;
  }

  FusedP fp;
  fp.inp = inp; fp.Wih0 = Wih0; fp.Whh0 = Whh0; fp.Wih1 = Wih1; fp.Whh1 = Whh1;
  fp.Wout = Wout; fp.ctx = ctx; fp.ctxp = ctxp;
  fp.bih0 = bih0; fp.bhh0 = bhh0; fp.bih1 = bih1; fp.bhh1 = bhh1;
  fp.c0in = c0in;
  fp.h0b = h0b; fp.h1b = h1b; fp.fdb = fdb; fp.cvb = cvb; fp.psb = psb;
  fp.outs = outs; fp.hF = hF; fp.cF = cF; fp.attns = attns;
  fp.flags = flags;
  void* kargs[] = {(void*)&fp};
  hipLaunchCooperativeKernel(k_fused, dim3(256), dim3(256), kargs,
                             (unsigned)SMEM_BYTES, stream);
}

// Round 6
// 3919.683 us; speedup vs baseline: 2.2842x; 1.3614x over previous
//
#include <hip/hip_runtime.h>

#define T_ 64
#define B_ 64
#define S_ 128
#define E_ 512
#define H_ 1024
#define BH (B_ * H_)

// LDS weight slice geometry (bf16 elements), +8 pad => row stride = 4 banks
#define W0ROW (E_ + 2 * H_ + 8)   // 2568
#define W1ROW (2 * H_ + 8)        // 2056
#define SMEM_BYTES ((16 * W0ROW + 16 * W1ROW) * 2)  // 147968 B

typedef __attribute__((ext_vector_type(8))) short short8;
typedef __attribute__((ext_vector_type(4))) short short4v;
typedef __attribute__((ext_vector_type(4))) float f32x4;
typedef __attribute__((ext_vector_type(2))) float f32x2;

static __device__ __forceinline__ float bf2f(ushort u) {
  union { float f; unsigned u; } x; x.u = ((unsigned)u) << 16; return x.f;
}
static __device__ __forceinline__ ushort f2bf(float f) {
  union { float f; unsigned u; } x; x.f = f;
  unsigned r = 0x7FFFu + ((x.u >> 16) & 1u);
  return (ushort)((x.u + r) >> 16);
}
static __device__ __forceinline__ float sigm(float x) {
  return 1.f / (1.f + expf(-x));
}

// device-scope (sc1) relaxed atomics: write-through to the coherence point.
static __device__ __forceinline__ void st32_dev(unsigned* p, unsigned v) {
  __hip_atomic_store(p, v, __ATOMIC_RELAXED, __HIP_MEMORY_SCOPE_AGENT);
}
static __device__ __forceinline__ unsigned ld32_dev(const unsigned* p) {
  return __hip_atomic_load(p, __ATOMIC_RELAXED, __HIP_MEMORY_SCOPE_AGENT);
}
static __device__ __forceinline__ void stf_dev(float* p, float v) {
  union { float f; unsigned u; } x; x.f = v;
  st32_dev((unsigned*)p, x.u);
}

// ---------------------------------------------------------------------------
__global__ __launch_bounds__(256) void k_cvt(const float* __restrict__ src,
                                             ushort* __restrict__ dst, int n4) {
  int i = blockIdx.x * 256 + threadIdx.x;
  if (i >= n4) return;
  f32x4 v = ((const f32x4*)src)[i];
  short4v o;
  o[0] = (short)f2bf(v[0]); o[1] = (short)f2bf(v[1]);
  o[2] = (short)f2bf(v[2]); o[3] = (short)f2bf(v[3]);
  ((short4v*)dst)[i] = o;
}

// ---------------------------------------------------------------------------
// f32 (H,H) [k][d]  ->  bf16 (H,H) [d][k]  (transpose + convert, LDS tiled)
__global__ __launch_bounds__(256) void k_cvtT(const float* __restrict__ src,
                                              ushort* __restrict__ dst) {
  __shared__ ushort tile[32][33];
  const int bx = blockIdx.x & 31;   // d-tile
  const int by = blockIdx.x >> 5;   // k-tile
  const int lx = threadIdx.x & 31, ly = threadIdx.x >> 5;  // 32 x 8
#pragma unroll
  for (int i = 0; i < 32; i += 8)
    tile[ly + i][lx] = f2bf(src[(size_t)(by * 32 + ly + i) * H_ + bx * 32 + lx]);
  __syncthreads();
#pragma unroll
  for (int i = 0; i < 32; i += 8)
    dst[(size_t)(bx * 32 + ly + i) * H_ + by * 32 + lx] = tile[lx][ly + i];
}

// ---------------------------------------------------------------------------
// ctxp[m, d] = sum_k ctx[m, k] * WaT[d, k],  m = s*B+b.  bf16 output.
__global__ __launch_bounds__(256) void k_ctxp(const ushort* __restrict__ ctx,
                                              const ushort* __restrict__ WaT,
                                              ushort* __restrict__ ctxp) {
  const int tid = threadIdx.x;
  const int wave = tid >> 6, lane = tid & 63;
  const int quad = lane >> 4, l16 = lane & 15;
  const int m0 = blockIdx.x * 64 + wave * 16;
  const int n0 = blockIdx.y * 64;
  const ushort* ar = ctx + (size_t)(m0 + l16) * H_;
  const int koff = quad * 8;
  f32x4 acc[4] = {};
  for (int k0 = 0; k0 < H_; k0 += 32) {
    int kk = k0 + koff;
    short8 a = *(const short8*)(ar + kk);
#pragma unroll
    for (int nt = 0; nt < 4; ++nt) {
      short8 b = *(const short8*)(WaT + (size_t)(n0 + nt * 16 + l16) * H_ + kk);
      acc[nt] = __builtin_amdgcn_mfma_f32_16x16x32_bf16(a, b, acc[nt], 0, 0, 0);
    }
  }
#pragma unroll
  for (int nt = 0; nt < 4; ++nt)
#pragma unroll
    for (int r = 0; r < 4; ++r)
      ctxp[(size_t)(m0 + quad * 4 + r) * H_ + n0 + nt * 16 + l16] =
          f2bf(acc[nt][r]);
}

// ---------------------------------------------------------------------------
__global__ __launch_bounds__(256) void k_init(const float* __restrict__ h0in,
                                              ushort* __restrict__ h0b,
                                              ushort* __restrict__ h1b,
                                              ushort* __restrict__ fdb,
                                              unsigned* __restrict__ flags) {
  int i = blockIdx.x * 256 + threadIdx.x;
  h0b[i] = f2bf(h0in[i]);
  h1b[i] = f2bf(h0in[BH + i]);
  fdb[i] = 0;
  if (blockIdx.x == 0) flags[threadIdx.x * 16] = 0;
}

// ---------------------------------------------------------------------------
// Grid barrier (round-3 proven): block 0 collects per-block arrival flags,
// broadcasts via flags[0]. sc1 stores reach the coherence point;
// __syncthreads drains vmcnt. No cache-invalidating fences.
// 512-thread blocks: only tid<256 poll in block 0 (256 blocks total).
static __device__ __forceinline__ void grid_bar(unsigned* flags, unsigned gen) {
  __syncthreads();
  if (blockIdx.x == 0) {
    const int tid = threadIdx.x;
    if (tid > 0 && tid < 256) {
      while (ld32_dev(&flags[tid * 16]) < gen) __builtin_amdgcn_s_sleep(4);
    }
    __syncthreads();
    if (tid == 0) st32_dev(&flags[0], gen);
    __syncthreads();
  } else {
    if (threadIdx.x == 0) {
      st32_dev(&flags[blockIdx.x * 16], gen);
      while (ld32_dev(&flags[0]) < gen) __builtin_amdgcn_s_sleep(4);
    }
    __syncthreads();
  }
  asm volatile("" ::: "memory");
}

// ---------------------------------------------------------------------------
struct FusedP {
  const ushort* inp;
  const ushort* Wih0; const ushort* Whh0;
  const ushort* Wih1; const ushort* Whh1;
  const ushort* Wout;
  const ushort* ctx;
  const ushort* ctxp;    // bf16 (S,B,H)
  const float* bih0; const float* bhh0;
  const float* bih1; const float* bhh1;
  const float* c0in;
  ushort* h0b;   // (T_+1) rotated (B,H) bf16 buffers -- write-once
  ushort* h1b;   // (T_+1)
  ushort* fdb;   // (T_+1)
  ushort* cvb;   // (T_)
  float* psb;    // (T_) rotated (B,S,4) f32 partial scores -- write-once
  float* outs; float* hF; float* cF; float* attns;
  unsigned* flags;
};

// st/red union macros over ub[]:  st[w][r][c] (8x16x17)  /  red[w][i] (8x256)
#define ST(w, r, c) ub[(w) * 272 + (r) * 17 + (c)]
#define RED(w, i)   ub[(w) * 256 + (i)]

// Persistent kernel: 256 blocks x 512 threads (8 waves/CU = 2/SIMD).
// Waves w and w+4 K-split each MFMA phase; partials summed via LDS.
// LSTM weights LDS-resident; 5 barriers/step.
__global__ __launch_bounds__(512, 1) void k_fused(FusedP p) {
  extern __shared__ ushort wlds[];          // [16*W0ROW] + [16*W1ROW]
  ushort* w0 = wlds;
  ushort* w1 = wlds + 16 * W0ROW;
  __shared__ float ub[2176];                // st / red union (8704 B)
  __shared__ float al[S_];
  const int blk = blockIdx.x;
  const int tid = threadIdx.x;
  const int wave = tid >> 6, lane = tid & 63;
  const int wg = wave & 3;                  // wave group (batch strip)
  const int kh = wave >> 2;                 // K-half
  const int quad = lane >> 4, l16 = lane & 15;
  const int j0 = blk * 4;

  // ---- stage this block's weight slice into LDS (once) ----
  for (int idx = tid; idx < 16 * 192; idx += 512) {   // Wih0
    int r = idx / 192, c = (idx % 192) * 8;
    int n = (r >> 2) * H_ + j0 + (r & 3);
    *(short8*)(w0 + r * W0ROW + c) =
        *(const short8*)(p.Wih0 + (size_t)n * (E_ + H_) + c);
  }
  for (int idx = tid; idx < 16 * 128; idx += 512) {   // Whh0
    int r = idx / 128, c = (idx % 128) * 8;
    int n = (r >> 2) * H_ + j0 + (r & 3);
    *(short8*)(w0 + r * W0ROW + (E_ + H_) + c) =
        *(const short8*)(p.Whh0 + (size_t)n * H_ + c);
  }
  for (int idx = tid; idx < 16 * 128; idx += 512) {   // Wih1
    int r = idx / 128, c = (idx % 128) * 8;
    int n = (r >> 2) * H_ + j0 + (r & 3);
    *(short8*)(w1 + r * W1ROW + c) =
        *(const short8*)(p.Wih1 + (size_t)n * H_ + c);
  }
  for (int idx = tid; idx < 16 * 128; idx += 512) {   // Whh1
    int r = idx / 128, c = (idx % 128) * 8;
    int n = (r >> 2) * H_ + j0 + (r & 3);
    *(short8*)(w1 + r * W1ROW + H_ + c) =
        *(const short8*)(p.Whh1 + (size_t)n * H_ + c);
  }
  __syncthreads();

  // cell ownership (tid<256): cell = tid -> b = tid>>2, jl = tid&3
  const int own_b = tid >> 2;
  const int own_jl = tid & 3;
  const int own_j = j0 + own_jl;
  const int own_idx = own_b * H_ + own_j;
  float c0reg = 0.f, c1reg = 0.f;
  float b0i = 0.f, b0f = 0.f, b0g = 0.f, b0o = 0.f;
  float b1i = 0.f, b1f = 0.f, b1g = 0.f, b1o = 0.f;
  if (tid < 256) {
    c0reg = p.c0in[own_idx];
    c1reg = p.c0in[BH + own_idx];
    b0i = p.bih0[own_j]          + p.bhh0[own_j];
    b0f = p.bih0[H_ + own_j]     + p.bhh0[H_ + own_j];
    b0g = p.bih0[2 * H_ + own_j] + p.bhh0[2 * H_ + own_j];
    b0o = p.bih0[3 * H_ + own_j] + p.bhh0[3 * H_ + own_j];
    b1i = p.bih1[own_j]          + p.bhh1[own_j];
    b1f = p.bih1[H_ + own_j]     + p.bhh1[H_ + own_j];
    b1g = p.bih1[2 * H_ + own_j] + p.bhh1[2 * H_ + own_j];
    b1o = p.bih1[3 * H_ + own_j] + p.bhh1[3 * H_ + own_j];
  }

  const ushort* w0r = w0 + l16 * W0ROW;   // B-fragment row for MFMA
  const ushort* w1r = w1 + l16 * W1ROW;
  const int koff = quad * 8;

  // attention decomposition: this block owns (b3, d-quarter dq)
  const int b3 = blk >> 2, dq = blk & 3;
  const int d0 = dq * 256;

  unsigned gen = 0;

  for (int t = 0; t < T_; ++t) {
    const ushort* h0prev = p.h0b + (size_t)t * BH;
    ushort* h0new       = p.h0b + (size_t)(t + 1) * BH;
    const ushort* h1prev = p.h1b + (size_t)t * BH;
    ushort* h1new       = p.h1b + (size_t)(t + 1) * BH;
    const ushort* feedr  = p.fdb + (size_t)t * BH;
    ushort* feedw       = p.fdb + (size_t)(t + 1) * BH;
    ushort* cv          = p.cvb + (size_t)t * BH;
    float* pst          = p.psb + (size_t)t * B_ * S_ * 4;
    const int last = (t == T_ - 1);

    // ---- phase 1: LSTM layer 0, K-split across wave pairs ----
    {
      const int arow = 16 * wg + l16;
      const ushort* er = p.inp + ((size_t)t * B_ + arow) * E_;
      const ushort* fr = feedr + (size_t)arow * H_;
      const ushort* hr = h0prev + (size_t)arow * H_;
      const int kbase = kh * 1280;          // (E+2H)/2
      f32x4 acc = {};
      for (int k0 = 0; k0 < 1280; k0 += 32) {
        int kk = kbase + k0 + koff;
        short8 a;
        if (kk < E_)            a = *(const short8*)(er + kk);
        else if (kk < E_ + H_)  a = *(const short8*)(fr + (kk - E_));
        else                    a = *(const short8*)(hr + (kk - E_ - H_));
        short8 b = *(const short8*)(w0r + kk);
        acc = __builtin_amdgcn_mfma_f32_16x16x32_bf16(a, b, acc, 0, 0, 0);
      }
#pragma unroll
      for (int r = 0; r < 4; ++r) ST(wave, quad * 4 + r, l16) = acc[r];
      __syncthreads();
      if (tid < 256) {
        const int w = own_b >> 4, bl = own_b & 15;
        float gi = ST(w, bl, 0 + own_jl)  + ST(w + 4, bl, 0 + own_jl)  + b0i;
        float gf = ST(w, bl, 4 + own_jl)  + ST(w + 4, bl, 4 + own_jl)  + b0f;
        float gg = ST(w, bl, 8 + own_jl)  + ST(w + 4, bl, 8 + own_jl)  + b0g;
        float go = ST(w, bl, 12 + own_jl) + ST(w + 4, bl, 12 + own_jl) + b0o;
        float cn = sigm(gf) * c0reg + sigm(gi) * tanhf(gg);
        float hn = sigm(go) * tanhf(cn);
        c0reg = cn;
        if (last) { p.hF[own_idx] = hn; p.cF[own_idx] = cn; }
        unsigned u = f2bf(hn);
        unsigned up = __shfl_down(u, 1);
        if (!(own_jl & 1))
          st32_dev((unsigned*)h0new + own_b * (H_ / 2) + blk * 2 + (own_jl >> 1),
                   u | (up << 16));
      }
    }
    grid_bar(p.flags, ++gen);

    // ---- phase 2: LSTM layer 1, K-split across wave pairs ----
    {
      const int arow = 16 * wg + l16;
      const ushort* xr = h0new + (size_t)arow * H_;
      const ushort* hr = h1prev + (size_t)arow * H_;
      const int kbase = kh * 1024;          // 2H/2
      f32x4 acc = {};
      for (int k0 = 0; k0 < 1024; k0 += 32) {
        int kk = kbase + k0 + koff;
        short8 a = (kk < H_) ? *(const short8*)(xr + kk)
                             : *(const short8*)(hr + (kk - H_));
        short8 b = *(const short8*)(w1r + kk);
        acc = __builtin_amdgcn_mfma_f32_16x16x32_bf16(a, b, acc, 0, 0, 0);
      }
#pragma unroll
      for (int r = 0; r < 4; ++r) ST(wave, quad * 4 + r, l16) = acc[r];
      __syncthreads();
      if (tid < 256) {
        const int w = own_b >> 4, bl = own_b & 15;
        float gi = ST(w, bl, 0 + own_jl)  + ST(w + 4, bl, 0 + own_jl)  + b1i;
        float gf = ST(w, bl, 4 + own_jl)  + ST(w + 4, bl, 4 + own_jl)  + b1f;
        float gg = ST(w, bl, 8 + own_jl)  + ST(w + 4, bl, 8 + own_jl)  + b1g;
        float go = ST(w, bl, 12 + own_jl) + ST(w + 4, bl, 12 + own_jl) + b1o;
        float cn = sigm(gf) * c1reg + sigm(gi) * tanhf(gg);
        float hn = sigm(go) * tanhf(cn);
        c1reg = cn;
        if (last) { p.hF[BH + own_idx] = hn; p.cF[BH + own_idx] = cn; }
        unsigned u = f2bf(hn);
        unsigned up = __shfl_down(u, 1);
        if (!(own_jl & 1))
          st32_dev((unsigned*)h1new + own_b * (H_ / 2) + blk * 2 + (own_jl >> 1),
                   u | (up << 16));
      }
    }
    grid_bar(p.flags, ++gen);

    // ---- phase 3a: partial scores over this block's d-quarter ----
    {
      short4v qv = *(const short4v*)(h1new + (size_t)b3 * H_ + d0 + lane * 4);
      float q0 = bf2f((ushort)qv[0]), q1 = bf2f((ushort)qv[1]);
      float q2 = bf2f((ushort)qv[2]), q3 = bf2f((ushort)qv[3]);
#pragma unroll 4
      for (int i = 0; i < 16; ++i) {
        const int s = wave * 16 + i;
        short4v v = *(const short4v*)(p.ctxp + ((size_t)s * B_ + b3) * H_ +
                                      d0 + lane * 4);
        float pr = bf2f((ushort)v[0]) * q0 + bf2f((ushort)v[1]) * q1 +
                   bf2f((ushort)v[2]) * q2 + bf2f((ushort)v[3]) * q3;
#pragma unroll
        for (int off = 32; off; off >>= 1) pr += __shfl_down(pr, off);
        if (lane == 0) stf_dev(pst + (b3 * S_ + s) * 4 + dq, pr);
      }
    }
    grid_bar(p.flags, ++gen);

    // ---- phase 3b: reduce + softmax + cvec d-quarter ----
    {
      if (tid < S_) {
        f32x4 ps = *(const f32x4*)(pst + (b3 * S_ + tid) * 4);
        al[tid] = ps[0] + ps[1] + ps[2] + ps[3];
      }
      __syncthreads();
      if (wave == 0) {
        float m = fmaxf(al[lane], al[lane + 64]);
#pragma unroll
        for (int off = 32; off; off >>= 1) m = fmaxf(m, __shfl_down(m, off));
        m = __shfl(m, 0);
        float e0 = expf(al[lane] - m), e1 = expf(al[lane + 64] - m);
        float s2 = e0 + e1;
#pragma unroll
        for (int off = 32; off; off >>= 1) s2 += __shfl_down(s2, off);
        s2 = __shfl(s2, 0);
        float inv = 1.f / s2;
        al[lane] = e0 * inv;
        al[lane + 64] = e1 * inv;
      }
      __syncthreads();
      if (dq == 0 && tid < S_)
        p.attns[((size_t)t * B_ + b3) * S_ + tid] = al[tid];
      // cvec over d-quarter: wave w covers s in [16w,16w+16), 4 d per lane
      float a0 = 0.f, a1 = 0.f, a2 = 0.f, a3 = 0.f;
#pragma unroll 4
      for (int i = 0; i < 16; ++i) {
        const int s = wave * 16 + i;
        short4v v = *(const short4v*)(p.ctx + ((size_t)s * B_ + b3) * H_ +
                                      d0 + lane * 4);
        float w = al[s];
        a0 += w * bf2f((ushort)v[0]);
        a1 += w * bf2f((ushort)v[1]);
        a2 += w * bf2f((ushort)v[2]);
        a3 += w * bf2f((ushort)v[3]);
      }
      __syncthreads();   // al/softmax reads done; ub reuse is safe (post-P2)
      RED(wave, lane * 4 + 0) = a0;
      RED(wave, lane * 4 + 1) = a1;
      RED(wave, lane * 4 + 2) = a2;
      RED(wave, lane * 4 + 3) = a3;
      __syncthreads();
      if (tid < 256) {
        float val = 0.f;
#pragma unroll
        for (int w = 0; w < 8; ++w) val += RED(w, tid);
        unsigned u = f2bf(val);
        unsigned up = __shfl_down(u, 1);
        if (!(tid & 1))
          st32_dev((unsigned*)cv + (b3 * H_ + d0 + tid) / 2, u | (up << 16));
      }
    }
    grid_bar(p.flags, ++gen);

    // ---- phase 4: output projection, blocks 0..63, K-split wave pairs ----
    if (blk < 64) {
      const int pj0 = blk * 16;
      const int arow = 16 * wg + l16;
      const ushort* cr = cv + (size_t)arow * H_;
      const ushort* hr2 = h1new + (size_t)arow * H_;
      const ushort* wr = p.Wout + (size_t)(pj0 + l16) * (2 * H_);
      const int kbase = kh * 1024;
      f32x4 acc = {};
      for (int k0 = 0; k0 < 1024; k0 += 32) {
        int kk = kbase + k0 + koff;
        short8 a = (kk < H_) ? *(const short8*)(cr + kk)
                             : *(const short8*)(hr2 + (kk - H_));
        short8 b = *(const short8*)(wr + kk);
        acc = __builtin_amdgcn_mfma_f32_16x16x32_bf16(a, b, acc, 0, 0, 0);
      }
#pragma unroll
      for (int r = 0; r < 4; ++r) ST(wave, quad * 4 + r, l16) = acc[r];
      __syncthreads();
      {
        // 1024 outputs (64 b x 16 j), 2 consecutive j per thread
        const int b = tid >> 3;
        const int jl = (tid & 7) * 2;
        const int w = b >> 4, bl = b & 15;
        float v0 = tanhf(ST(w, bl, jl)     + ST(w + 4, bl, jl));
        float v1 = tanhf(ST(w, bl, jl + 1) + ST(w + 4, bl, jl + 1));
        f32x2 o2; o2[0] = v0; o2[1] = v1;
        *(f32x2*)(p.outs + (size_t)t * B_ * H_ + b * H_ + pj0 + jl) = o2;
        st32_dev((unsigned*)feedw + b * (H_ / 2) + blk * 8 + (jl >> 1),
                 (unsigned)f2bf(v0) | ((unsigned)f2bf(v1) << 16));
      }
    }
    grid_bar(p.flags, ++gen);
  }
}

// ---------------------------------------------------------------------------
extern "C" void kernel_launch(void* const* d_in, const int* in_sizes, int n_in,
                              void* d_out, int out_size, void* d_ws, size_t ws_size,
                              hipStream_t stream) {
  const float* inpf  = (const float*)d_in[0];
  const float* ctxf  = (const float*)d_in[1];
  const float* h0in  = (const float*)d_in[2];
  const float* c0in  = (const float*)d_in[3];
  const float* Wih0f = (const float*)d_in[4];
  const float* bih0  = (const float*)d_in[5];
  const float* Whh0f = (const float*)d_in[6];
  const float* bhh0  = (const float*)d_in[7];
  const float* Wih1f = (const float*)d_in[8];
  const float* bih1  = (const float*)d_in[9];
  const float* Whh1f = (const float*)d_in[10];
  const float* bhh1  = (const float*)d_in[11];
  const float* Waf   = (const float*)d_in[12];
  const float* Woutf = (const float*)d_in[13];

  float* out = (float*)d_out;
  float* outs  = out;                              // (T,B,H)
  float* hF    = out + (size_t)T_ * B_ * H_;       // (2,B,H)
  float* cF    = hF + 2 * BH;                      // (2,B,H)
  float* attns = cF + 2 * BH;                      // (T,B,S)

  char* p = (char*)d_ws;
  auto take = [&](size_t bytes) -> char* {
    char* q = p;
    p += (bytes + 255) & ~(size_t)255;
    return q;
  };
  ushort* h0b  = (ushort*)take((size_t)(T_ + 1) * BH * 2);
  ushort* h1b  = (ushort*)take((size_t)(T_ + 1) * BH * 2);
  ushort* fdb  = (ushort*)take((size_t)(T_ + 1) * BH * 2);
  ushort* cvb  = (ushort*)take((size_t)T_ * BH * 2);
  float* psb   = (float*)take((size_t)T_ * B_ * S_ * 4 * 4);
  unsigned* flags = (unsigned*)take(256 * 16 * sizeof(unsigned));
  ushort* WaT  = (ushort*)take((size_t)H_ * H_ * 2);
  ushort* ctxp = (ushort*)take((size_t)S_ * B_ * H_ * 2);

  struct { const float* src; int n; } cv[7] = {
    {Wih0f, 4 * H_ * (E_ + H_)}, {Whh0f, 4 * H_ * H_},
    {Wih1f, 4 * H_ * H_},        {Whh1f, 4 * H_ * H_},
    {Woutf, 2 * H_ * H_},
    {inpf,  T_ * B_ * E_},       {ctxf,  S_ * B_ * H_},
  };
  ushort* cb[7];
  for (int i = 0; i < 7; ++i) {
    cb[i] = (ushort*)take((size_t)cv[i].n * 2);
    int n4 = cv[i].n / 4;
    k_cvt<<<(n4 + 255) / 256, 256, 0, stream>>>(cv[i].src, cb[i], n4);
  }
  const ushort *Wih0 = cb[0], *Whh0 = cb[1], *Wih1 = cb[2], *Whh1 = cb[3],
               *Wout = cb[4], *inp = cb[5], *ctx = cb[6];

  k_cvtT<<<(H_ / 32) * (H_ / 32), 256, 0, stream>>>(Waf, WaT);
  k_ctxp<<<dim3((S_ * B_) / 64, H_ / 64), 256, 0, stream>>>(ctx, WaT, ctxp);
  k_init<<<BH / 256, 256, 0, stream>>>(h0in, h0b, h1b, fdb, flags);

  static int smem_set = 0;
  if (!smem_set) {
    hipFuncSetAttribute((const void*)k_fused,
                        hipFuncAttributeMaxDynamicSharedMemorySize, SMEM_BYTES);
    smem_set = 1;
  }

  FusedP fp;
  fp.inp = inp; fp.Wih0 = Wih0; fp.Whh0 = Whh0; fp.Wih1 = Wih1; fp.Whh1 = Whh1;
  fp.Wout = Wout; fp.ctx = ctx; fp.ctxp = ctxp;
  fp.bih0 = bih0; fp.bhh0 = bhh0; fp.bih1 = bih1; fp.bhh1 = bhh1;
  fp.c0in = c0in;
  fp.h0b = h0b; fp.h1b = h1b; fp.fdb = fdb; fp.cvb = cvb; fp.psb = psb;
  fp.outs = outs; fp.hF = hF; fp.cF = cF; fp.attns = attns;
  fp.flags = flags;
  void* kargs[] = {(void*)&fp};
  hipLaunchCooperativeKernel(k_fused, dim3(256), dim3(512), kargs,
                             (unsigned)SMEM_BYTES, stream);
}

// Round 7
// 3566.544 us; speedup vs baseline: 2.5104x; 1.0990x over previous
//
#include <hip/hip_runtime.h>

#define T_ 64
#define B_ 64
#define S_ 128
#define E_ 512
#define H_ 1024
#define BH (B_ * H_)

// LDS weight slice geometry (bf16 elements), +8 pad => row stride = 4 banks
#define W0ROW (E_ + 2 * H_ + 8)   // 2568
#define W1ROW (2 * H_ + 8)        // 2056
#define SMEM_BYTES ((16 * W0ROW + 16 * W1ROW) * 2)  // 147968 B

typedef __attribute__((ext_vector_type(8))) short short8;
typedef __attribute__((ext_vector_type(4))) short short4v;
typedef __attribute__((ext_vector_type(4))) float f32x4;

static __device__ __forceinline__ float bf2f(ushort u) {
  union { float f; unsigned u; } x; x.u = ((unsigned)u) << 16; return x.f;
}
static __device__ __forceinline__ ushort f2bf(float f) {
  union { float f; unsigned u; } x; x.f = f;
  unsigned r = 0x7FFFu + ((x.u >> 16) & 1u);
  return (ushort)((x.u + r) >> 16);
}
static __device__ __forceinline__ float sigm(float x) {
  return 1.f / (1.f + expf(-x));
}

// device-scope (sc1) relaxed atomics: write-through to the coherence point.
static __device__ __forceinline__ void st32_dev(unsigned* p, unsigned v) {
  __hip_atomic_store(p, v, __ATOMIC_RELAXED, __HIP_MEMORY_SCOPE_AGENT);
}
static __device__ __forceinline__ unsigned ld32_dev(const unsigned* p) {
  return __hip_atomic_load(p, __ATOMIC_RELAXED, __HIP_MEMORY_SCOPE_AGENT);
}
static __device__ __forceinline__ void stf_dev(float* p, float v) {
  union { float f; unsigned u; } x; x.f = v;
  st32_dev((unsigned*)p, x.u);
}

// ---------------------------------------------------------------------------
__global__ __launch_bounds__(256) void k_cvt(const float* __restrict__ src,
                                             ushort* __restrict__ dst, int n4) {
  int i = blockIdx.x * 256 + threadIdx.x;
  if (i >= n4) return;
  f32x4 v = ((const f32x4*)src)[i];
  short4v o;
  o[0] = (short)f2bf(v[0]); o[1] = (short)f2bf(v[1]);
  o[2] = (short)f2bf(v[2]); o[3] = (short)f2bf(v[3]);
  ((short4v*)dst)[i] = o;
}

// ---------------------------------------------------------------------------
// f32 (H,H) [k][d]  ->  bf16 (H,H) [d][k]  (transpose + convert, LDS tiled)
__global__ __launch_bounds__(256) void k_cvtT(const float* __restrict__ src,
                                              ushort* __restrict__ dst) {
  __shared__ ushort tile[32][33];
  const int bx = blockIdx.x & 31;   // d-tile
  const int by = blockIdx.x >> 5;   // k-tile
  const int lx = threadIdx.x & 31, ly = threadIdx.x >> 5;  // 32 x 8
#pragma unroll
  for (int i = 0; i < 32; i += 8)
    tile[ly + i][lx] = f2bf(src[(size_t)(by * 32 + ly + i) * H_ + bx * 32 + lx]);
  __syncthreads();
#pragma unroll
  for (int i = 0; i < 32; i += 8)
    dst[(size_t)(bx * 32 + ly + i) * H_ + by * 32 + lx] = tile[lx][ly + i];
}

// ---------------------------------------------------------------------------
// ctxp[m, d] = sum_k ctx[m, k] * WaT[d, k],  m = s*B+b.  bf16 output.
__global__ __launch_bounds__(256) void k_ctxp(const ushort* __restrict__ ctx,
                                              const ushort* __restrict__ WaT,
                                              ushort* __restrict__ ctxp) {
  const int tid = threadIdx.x;
  const int wave = tid >> 6, lane = tid & 63;
  const int quad = lane >> 4, l16 = lane & 15;
  const int m0 = blockIdx.x * 64 + wave * 16;
  const int n0 = blockIdx.y * 64;
  const ushort* ar = ctx + (size_t)(m0 + l16) * H_;
  const int koff = quad * 8;
  f32x4 acc[4] = {};
  for (int k0 = 0; k0 < H_; k0 += 32) {
    int kk = k0 + koff;
    short8 a = *(const short8*)(ar + kk);
#pragma unroll
    for (int nt = 0; nt < 4; ++nt) {
      short8 b = *(const short8*)(WaT + (size_t)(n0 + nt * 16 + l16) * H_ + kk);
      acc[nt] = __builtin_amdgcn_mfma_f32_16x16x32_bf16(a, b, acc[nt], 0, 0, 0);
    }
  }
#pragma unroll
  for (int nt = 0; nt < 4; ++nt)
#pragma unroll
    for (int r = 0; r < 4; ++r)
      ctxp[(size_t)(m0 + quad * 4 + r) * H_ + n0 + nt * 16 + l16] =
          f2bf(acc[nt][r]);
}

// ---------------------------------------------------------------------------
__global__ __launch_bounds__(256) void k_init(const float* __restrict__ h0in,
                                              ushort* __restrict__ h0b,
                                              ushort* __restrict__ h1b,
                                              ushort* __restrict__ fdb,
                                              unsigned* __restrict__ flags) {
  int i = blockIdx.x * 256 + threadIdx.x;
  h0b[i] = f2bf(h0in[i]);
  h1b[i] = f2bf(h0in[BH + i]);
  fdb[i] = 0;
  if (blockIdx.x == 0) flags[threadIdx.x * 16] = 0;
}

// ---------------------------------------------------------------------------
// Grid barrier (round-3 proven): block 0 collects per-block arrival flags,
// broadcasts via flags[0]. sc1 stores reach the coherence point;
// __syncthreads drains vmcnt. No cache-invalidating fences.
// 1024-thread blocks: only tid<256 poll in block 0 (256 blocks total).
static __device__ __forceinline__ void grid_bar(unsigned* flags, unsigned gen) {
  __syncthreads();
  if (blockIdx.x == 0) {
    const int tid = threadIdx.x;
    if (tid > 0 && tid < 256) {
      while (ld32_dev(&flags[tid * 16]) < gen) __builtin_amdgcn_s_sleep(4);
    }
    __syncthreads();
    if (tid == 0) st32_dev(&flags[0], gen);
    __syncthreads();
  } else {
    if (threadIdx.x == 0) {
      st32_dev(&flags[blockIdx.x * 16], gen);
      while (ld32_dev(&flags[0]) < gen) __builtin_amdgcn_s_sleep(4);
    }
    __syncthreads();
  }
  asm volatile("" ::: "memory");
}

// ---------------------------------------------------------------------------
struct FusedP {
  const ushort* inp;
  const ushort* Wih0; const ushort* Whh0;
  const ushort* Wih1; const ushort* Whh1;
  const ushort* Wout;
  const ushort* ctx;
  const ushort* ctxp;    // bf16 (S,B,H)
  const float* bih0; const float* bhh0;
  const float* bih1; const float* bhh1;
  const float* c0in;
  ushort* h0b;   // (T_+1) rotated (B,H) bf16 buffers -- write-once
  ushort* h1b;   // (T_+1)
  ushort* fdb;   // (T_+1)
  ushort* cvb;   // (T_)
  float* psb;    // (T_) rotated (B,S,4) f32 partial scores -- write-once
  float* outs; float* hF; float* cF; float* attns;
  unsigned* flags;
};

// st/red union over ub[]:  st[w][r][c] (8x16x17)  /  red[w][i] (8x256)
#define ST(w, r, c) ub[(w) * 272 + (r) * 17 + (c)]
#define RED(w, i)   ub[(w) * 256 + (i)]

// Persistent kernel: 256 blocks x 1024 threads (16 waves/CU = 4/SIMD).
// Each MFMA phase K-splits 4-way across wave quartets (kh = wave>>2);
// partials merge via two-stage LDS reduction in the 8-slot ub buffer:
//   stage1: kh>=2 waves park acc in slot (wave-8)
//   stage2: kh<2 waves rmw their own slot (wave) adding the parked partial
//   epilogue: strip w total = ST(w) + ST(w+4)
// LSTM weights LDS-resident; 5 barriers/step.
__global__ __launch_bounds__(1024, 1) void k_fused(FusedP p) {
  extern __shared__ ushort wlds[];          // [16*W0ROW] + [16*W1ROW]
  ushort* w0 = wlds;
  ushort* w1 = wlds + 16 * W0ROW;
  __shared__ float ub[2176];                // st / red union (8704 B)
  __shared__ float al[S_];
  const int blk = blockIdx.x;
  const int tid = threadIdx.x;
  const int wave = tid >> 6, lane = tid & 63;
  const int wg = wave & 3;                  // batch strip
  const int kh = wave >> 2;                 // K-quarter
  const int quad = lane >> 4, l16 = lane & 15;
  const int j0 = blk * 4;

  // ---- stage this block's weight slice into LDS (once) ----
  for (int idx = tid; idx < 16 * 192; idx += 1024) {   // Wih0
    int r = idx / 192, c = (idx % 192) * 8;
    int n = (r >> 2) * H_ + j0 + (r & 3);
    *(short8*)(w0 + r * W0ROW + c) =
        *(const short8*)(p.Wih0 + (size_t)n * (E_ + H_) + c);
  }
  for (int idx = tid; idx < 16 * 128; idx += 1024) {   // Whh0
    int r = idx / 128, c = (idx % 128) * 8;
    int n = (r >> 2) * H_ + j0 + (r & 3);
    *(short8*)(w0 + r * W0ROW + (E_ + H_) + c) =
        *(const short8*)(p.Whh0 + (size_t)n * H_ + c);
  }
  for (int idx = tid; idx < 16 * 128; idx += 1024) {   // Wih1
    int r = idx / 128, c = (idx % 128) * 8;
    int n = (r >> 2) * H_ + j0 + (r & 3);
    *(short8*)(w1 + r * W1ROW + c) =
        *(const short8*)(p.Wih1 + (size_t)n * H_ + c);
  }
  for (int idx = tid; idx < 16 * 128; idx += 1024) {   // Whh1
    int r = idx / 128, c = (idx % 128) * 8;
    int n = (r >> 2) * H_ + j0 + (r & 3);
    *(short8*)(w1 + r * W1ROW + H_ + c) =
        *(const short8*)(p.Whh1 + (size_t)n * H_ + c);
  }
  __syncthreads();

  // cell ownership (tid<256): cell = tid -> b = tid>>2, jl = tid&3
  const int own_b = tid >> 2;
  const int own_jl = tid & 3;
  const int own_j = j0 + own_jl;
  const int own_idx = own_b * H_ + own_j;
  float c0reg = 0.f, c1reg = 0.f;
  float b0i = 0.f, b0f = 0.f, b0g = 0.f, b0o = 0.f;
  float b1i = 0.f, b1f = 0.f, b1g = 0.f, b1o = 0.f;
  if (tid < 256) {
    c0reg = p.c0in[own_idx];
    c1reg = p.c0in[BH + own_idx];
    b0i = p.bih0[own_j]          + p.bhh0[own_j];
    b0f = p.bih0[H_ + own_j]     + p.bhh0[H_ + own_j];
    b0g = p.bih0[2 * H_ + own_j] + p.bhh0[2 * H_ + own_j];
    b0o = p.bih0[3 * H_ + own_j] + p.bhh0[3 * H_ + own_j];
    b1i = p.bih1[own_j]          + p.bhh1[own_j];
    b1f = p.bih1[H_ + own_j]     + p.bhh1[H_ + own_j];
    b1g = p.bih1[2 * H_ + own_j] + p.bhh1[2 * H_ + own_j];
    b1o = p.bih1[3 * H_ + own_j] + p.bhh1[3 * H_ + own_j];
  }

  const ushort* w0r = w0 + l16 * W0ROW;   // B-fragment row for MFMA
  const ushort* w1r = w1 + l16 * W1ROW;
  const int koff = quad * 8;

  // attention decomposition: this block owns (b3, d-quarter dq)
  const int b3 = blk >> 2, dq = blk & 3;
  const int d0 = dq * 256;

  unsigned gen = 0;

  for (int t = 0; t < T_; ++t) {
    const ushort* h0prev = p.h0b + (size_t)t * BH;
    ushort* h0new       = p.h0b + (size_t)(t + 1) * BH;
    const ushort* h1prev = p.h1b + (size_t)t * BH;
    ushort* h1new       = p.h1b + (size_t)(t + 1) * BH;
    const ushort* feedr  = p.fdb + (size_t)t * BH;
    ushort* feedw       = p.fdb + (size_t)(t + 1) * BH;
    ushort* cv          = p.cvb + (size_t)t * BH;
    float* pst          = p.psb + (size_t)t * B_ * S_ * 4;
    const int last = (t == T_ - 1);

    // ---- phase 1: LSTM layer 0, 4-way K-split ----
    {
      const int arow = 16 * wg + l16;
      const ushort* er = p.inp + ((size_t)t * B_ + arow) * E_;
      const ushort* fr = feedr + (size_t)arow * H_;
      const ushort* hr = h0prev + (size_t)arow * H_;
      const int kbase = kh * 640;           // (E+2H)/4
      f32x4 acc = {};
#pragma unroll
      for (int k0 = 0; k0 < 640; k0 += 32) {
        int kk = kbase + k0 + koff;
        short8 a;
        if (kk < E_)            a = *(const short8*)(er + kk);
        else if (kk < E_ + H_)  a = *(const short8*)(fr + (kk - E_));
        else                    a = *(const short8*)(hr + (kk - E_ - H_));
        short8 b = *(const short8*)(w0r + kk);
        acc = __builtin_amdgcn_mfma_f32_16x16x32_bf16(a, b, acc, 0, 0, 0);
      }
      if (kh >= 2) {
#pragma unroll
        for (int r = 0; r < 4; ++r) ST(wave - 8, quad * 4 + r, l16) = acc[r];
      }
      __syncthreads();
      if (kh < 2) {
#pragma unroll
        for (int r = 0; r < 4; ++r) {
          float s = ST(wave, quad * 4 + r, l16) + acc[r];
          ST(wave, quad * 4 + r, l16) = s;
        }
      }
      __syncthreads();
      if (tid < 256) {
        const int w = own_b >> 4, bl = own_b & 15;
        float gi = ST(w, bl, 0 + own_jl)  + ST(w + 4, bl, 0 + own_jl)  + b0i;
        float gf = ST(w, bl, 4 + own_jl)  + ST(w + 4, bl, 4 + own_jl)  + b0f;
        float gg = ST(w, bl, 8 + own_jl)  + ST(w + 4, bl, 8 + own_jl)  + b0g;
        float go = ST(w, bl, 12 + own_jl) + ST(w + 4, bl, 12 + own_jl) + b0o;
        float cn = sigm(gf) * c0reg + sigm(gi) * tanhf(gg);
        float hn = sigm(go) * tanhf(cn);
        c0reg = cn;
        if (last) { p.hF[own_idx] = hn; p.cF[own_idx] = cn; }
        unsigned u = f2bf(hn);
        unsigned up = __shfl_down(u, 1);
        if (!(own_jl & 1))
          st32_dev((unsigned*)h0new + own_b * (H_ / 2) + blk * 2 + (own_jl >> 1),
                   u | (up << 16));
      }
    }
    grid_bar(p.flags, ++gen);

    // ---- phase 2: LSTM layer 1, 4-way K-split ----
    {
      const int arow = 16 * wg + l16;
      const ushort* xr = h0new + (size_t)arow * H_;
      const ushort* hr = h1prev + (size_t)arow * H_;
      const int kbase = kh * 512;           // 2H/4
      f32x4 acc = {};
#pragma unroll
      for (int k0 = 0; k0 < 512; k0 += 32) {
        int kk = kbase + k0 + koff;
        short8 a = (kk < H_) ? *(const short8*)(xr + kk)
                             : *(const short8*)(hr + (kk - H_));
        short8 b = *(const short8*)(w1r + kk);
        acc = __builtin_amdgcn_mfma_f32_16x16x32_bf16(a, b, acc, 0, 0, 0);
      }
      if (kh >= 2) {
#pragma unroll
        for (int r = 0; r < 4; ++r) ST(wave - 8, quad * 4 + r, l16) = acc[r];
      }
      __syncthreads();
      if (kh < 2) {
#pragma unroll
        for (int r = 0; r < 4; ++r) {
          float s = ST(wave, quad * 4 + r, l16) + acc[r];
          ST(wave, quad * 4 + r, l16) = s;
        }
      }
      __syncthreads();
      if (tid < 256) {
        const int w = own_b >> 4, bl = own_b & 15;
        float gi = ST(w, bl, 0 + own_jl)  + ST(w + 4, bl, 0 + own_jl)  + b1i;
        float gf = ST(w, bl, 4 + own_jl)  + ST(w + 4, bl, 4 + own_jl)  + b1f;
        float gg = ST(w, bl, 8 + own_jl)  + ST(w + 4, bl, 8 + own_jl)  + b1g;
        float go = ST(w, bl, 12 + own_jl) + ST(w + 4, bl, 12 + own_jl) + b1o;
        float cn = sigm(gf) * c1reg + sigm(gi) * tanhf(gg);
        float hn = sigm(go) * tanhf(cn);
        c1reg = cn;
        if (last) { p.hF[BH + own_idx] = hn; p.cF[BH + own_idx] = cn; }
        unsigned u = f2bf(hn);
        unsigned up = __shfl_down(u, 1);
        if (!(own_jl & 1))
          st32_dev((unsigned*)h1new + own_b * (H_ / 2) + blk * 2 + (own_jl >> 1),
                   u | (up << 16));
      }
    }
    grid_bar(p.flags, ++gen);

    // ---- phase 3a: partial scores, 16 waves x 8 s each ----
    {
      short4v qv = *(const short4v*)(h1new + (size_t)b3 * H_ + d0 + lane * 4);
      float q0 = bf2f((ushort)qv[0]), q1 = bf2f((ushort)qv[1]);
      float q2 = bf2f((ushort)qv[2]), q3 = bf2f((ushort)qv[3]);
#pragma unroll
      for (int i = 0; i < 8; ++i) {
        const int s = wave * 8 + i;
        short4v v = *(const short4v*)(p.ctxp + ((size_t)s * B_ + b3) * H_ +
                                      d0 + lane * 4);
        float pr = bf2f((ushort)v[0]) * q0 + bf2f((ushort)v[1]) * q1 +
                   bf2f((ushort)v[2]) * q2 + bf2f((ushort)v[3]) * q3;
#pragma unroll
        for (int off = 32; off; off >>= 1) pr += __shfl_down(pr, off);
        if (lane == 0) stf_dev(pst + (b3 * S_ + s) * 4 + dq, pr);
      }
    }
    grid_bar(p.flags, ++gen);

    // ---- phase 3b: reduce + softmax + cvec d-quarter ----
    {
      if (tid < S_) {
        f32x4 ps = *(const f32x4*)(pst + (b3 * S_ + tid) * 4);
        al[tid] = ps[0] + ps[1] + ps[2] + ps[3];
      }
      __syncthreads();
      if (wave == 0) {
        float m = fmaxf(al[lane], al[lane + 64]);
#pragma unroll
        for (int off = 32; off; off >>= 1) m = fmaxf(m, __shfl_down(m, off));
        m = __shfl(m, 0);
        float e0 = expf(al[lane] - m), e1 = expf(al[lane + 64] - m);
        float s2 = e0 + e1;
#pragma unroll
        for (int off = 32; off; off >>= 1) s2 += __shfl_down(s2, off);
        s2 = __shfl(s2, 0);
        float inv = 1.f / s2;
        al[lane] = e0 * inv;
        al[lane + 64] = e1 * inv;
      }
      __syncthreads();
      if (dq == 0 && tid < S_)
        p.attns[((size_t)t * B_ + b3) * S_ + tid] = al[tid];
      // cvec over d-quarter: wave w covers s in [8w, 8w+8), 4 d per lane
      float a0 = 0.f, a1 = 0.f, a2 = 0.f, a3 = 0.f;
#pragma unroll
      for (int i = 0; i < 8; ++i) {
        const int s = wave * 8 + i;
        short4v v = *(const short4v*)(p.ctx + ((size_t)s * B_ + b3) * H_ +
                                      d0 + lane * 4);
        float w = al[s];
        a0 += w * bf2f((ushort)v[0]);
        a1 += w * bf2f((ushort)v[1]);
        a2 += w * bf2f((ushort)v[2]);
        a3 += w * bf2f((ushort)v[3]);
      }
      __syncthreads();   // al reads done; ub reuse safe
      if (wave >= 8) {
        RED(wave - 8, lane * 4 + 0) = a0;
        RED(wave - 8, lane * 4 + 1) = a1;
        RED(wave - 8, lane * 4 + 2) = a2;
        RED(wave - 8, lane * 4 + 3) = a3;
      }
      __syncthreads();
      if (wave < 8) {
        RED(wave, lane * 4 + 0) += a0;
        RED(wave, lane * 4 + 1) += a1;
        RED(wave, lane * 4 + 2) += a2;
        RED(wave, lane * 4 + 3) += a3;
      }
      __syncthreads();
      if (tid < 256) {
        float val = 0.f;
#pragma unroll
        for (int w = 0; w < 8; ++w) val += RED(w, tid);
        unsigned u = f2bf(val);
        unsigned up = __shfl_down(u, 1);
        if (!(tid & 1))
          st32_dev((unsigned*)cv + (b3 * H_ + d0 + tid) / 2, u | (up << 16));
      }
    }
    grid_bar(p.flags, ++gen);

    // ---- phase 4: output projection, blocks 0..63, 4-way K-split ----
    if (blk < 64) {
      const int pj0 = blk * 16;
      const int arow = 16 * wg + l16;
      const ushort* cr = cv + (size_t)arow * H_;
      const ushort* hr2 = h1new + (size_t)arow * H_;
      const ushort* wr = p.Wout + (size_t)(pj0 + l16) * (2 * H_);
      const int kbase = kh * 512;
      f32x4 acc = {};
#pragma unroll
      for (int k0 = 0; k0 < 512; k0 += 32) {
        int kk = kbase + k0 + koff;
        short8 a = (kk < H_) ? *(const short8*)(cr + kk)
                             : *(const short8*)(hr2 + (kk - H_));
        short8 b = *(const short8*)(wr + kk);
        acc = __builtin_amdgcn_mfma_f32_16x16x32_bf16(a, b, acc, 0, 0, 0);
      }
      if (kh >= 2) {
#pragma unroll
        for (int r = 0; r < 4; ++r) ST(wave - 8, quad * 4 + r, l16) = acc[r];
      }
      __syncthreads();
      if (kh < 2) {
#pragma unroll
        for (int r = 0; r < 4; ++r) {
          float s = ST(wave, quad * 4 + r, l16) + acc[r];
          ST(wave, quad * 4 + r, l16) = s;
        }
      }
      __syncthreads();
      {
        // 1024 outputs (64 b x 16 j): exactly one per thread
        const int b = tid >> 4;
        const int jl = tid & 15;
        const int w = b >> 4, bl = b & 15;
        float v = tanhf(ST(w, bl, jl) + ST(w + 4, bl, jl));
        p.outs[(size_t)t * B_ * H_ + b * H_ + pj0 + jl] = v;
        unsigned u = f2bf(v);
        unsigned up = __shfl_down(u, 1);
        if (!(jl & 1))
          st32_dev((unsigned*)feedw + b * (H_ / 2) + blk * 8 + (jl >> 1),
                   u | (up << 16));
      }
    }
    grid_bar(p.flags, ++gen);
  }
}

// ---------------------------------------------------------------------------
extern "C" void kernel_launch(void* const* d_in, const int* in_sizes, int n_in,
                              void* d_out, int out_size, void* d_ws, size_t ws_size,
                              hipStream_t stream) {
  const float* inpf  = (const float*)d_in[0];
  const float* ctxf  = (const float*)d_in[1];
  const float* h0in  = (const float*)d_in[2];
  const float* c0in  = (const float*)d_in[3];
  const float* Wih0f = (const float*)d_in[4];
  const float* bih0  = (const float*)d_in[5];
  const float* Whh0f = (const float*)d_in[6];
  const float* bhh0  = (const float*)d_in[7];
  const float* Wih1f = (const float*)d_in[8];
  const float* bih1  = (const float*)d_in[9];
  const float* Whh1f = (const float*)d_in[10];
  const float* bhh1  = (const float*)d_in[11];
  const float* Waf   = (const float*)d_in[12];
  const float* Woutf = (const float*)d_in[13];

  float* out = (float*)d_out;
  float* outs  = out;                              // (T,B,H)
  float* hF    = out + (size_t)T_ * B_ * H_;       // (2,B,H)
  float* cF    = hF + 2 * BH;                      // (2,B,H)
  float* attns = cF + 2 * BH;                      // (T,B,S)

  char* p = (char*)d_ws;
  auto take = [&](size_t bytes) -> char* {
    char* q = p;
    p += (bytes + 255) & ~(size_t)255;
    return q;
  };
  ushort* h0b  = (ushort*)take((size_t)(T_ + 1) * BH * 2);
  ushort* h1b  = (ushort*)take((size_t)(T_ + 1) * BH * 2);
  ushort* fdb  = (ushort*)take((size_t)(T_ + 1) * BH * 2);
  ushort* cvb  = (ushort*)take((size_t)T_ * BH * 2);
  float* psb   = (float*)take((size_t)T_ * B_ * S_ * 4 * 4);
  unsigned* flags = (unsigned*)take(256 * 16 * sizeof(unsigned));
  ushort* WaT  = (ushort*)take((size_t)H_ * H_ * 2);
  ushort* ctxp = (ushort*)take((size_t)S_ * B_ * H_ * 2);

  struct { const float* src; int n; } cv[7] = {
    {Wih0f, 4 * H_ * (E_ + H_)}, {Whh0f, 4 * H_ * H_},
    {Wih1f, 4 * H_ * H_},        {Whh1f, 4 * H_ * H_},
    {Woutf, 2 * H_ * H_},
    {inpf,  T_ * B_ * E_},       {ctxf,  S_ * B_ * H_},
  };
  ushort* cb[7];
  for (int i = 0; i < 7; ++i) {
    cb[i] = (ushort*)take((size_t)cv[i].n * 2);
    int n4 = cv[i].n / 4;
    k_cvt<<<(n4 + 255) / 256, 256, 0, stream>>>(cv[i].src, cb[i], n4);
  }
  const ushort *Wih0 = cb[0], *Whh0 = cb[1], *Wih1 = cb[2], *Whh1 = cb[3],
               *Wout = cb[4], *inp = cb[5], *ctx = cb[6];

  k_cvtT<<<(H_ / 32) * (H_ / 32), 256, 0, stream>>>(Waf, WaT);
  k_ctxp<<<dim3((S_ * B_) / 64, H_ / 64), 256, 0, stream>>>(ctx, WaT, ctxp);
  k_init<<<BH / 256, 256, 0, stream>>>(h0in, h0b, h1b, fdb, flags);

  static int smem_set = 0;
  if (!smem_set) {
    hipFuncSetAttribute((const void*)k_fused,
                        hipFuncAttributeMaxDynamicSharedMemorySize, SMEM_BYTES);
    smem_set = 1;
  }

  FusedP fp;
  fp.inp = inp; fp.Wih0 = Wih0; fp.Whh0 = Whh0; fp.Wih1 = Wih1; fp.Whh1 = Whh1;
  fp.Wout = Wout; fp.ctx = ctx; fp.ctxp = ctxp;
  fp.bih0 = bih0; fp.bhh0 = bhh0; fp.bih1 = bih1; fp.bhh1 = bhh1;
  fp.c0in = c0in;
  fp.h0b = h0b; fp.h1b = h1b; fp.fdb = fdb; fp.cvb = cvb; fp.psb = psb;
  fp.outs = outs; fp.hF = hF; fp.cF = cF; fp.attns = attns;
  fp.flags = flags;
  void* kargs[] = {(void*)&fp};
  hipLaunchCooperativeKernel(k_fused, dim3(256), dim3(1024), kargs,
                             (unsigned)SMEM_BYTES, stream);
}